// Round 1
// baseline (3756.354 us; speedup 1.0000x reference)
//
#include <hip/hip_runtime.h>

#define N_NODES 20000
#define N_EDGES 320000
#define F_IN 4644
#define F_H 512
#define EPSV 1e-5f

// ---------------- utility kernels ----------------
__global__ void k_zero_i(int* p, int n){ int i = blockIdx.x*blockDim.x+threadIdx.x; if(i<n) p[i]=0; }
__global__ void k_zero_f(float* p, int n){ int i = blockIdx.x*blockDim.x+threadIdx.x; if(i<n) p[i]=0.f; }

__global__ void k_degree(const int* __restrict__ dst, int* __restrict__ deg){
  int e = blockIdx.x*blockDim.x+threadIdx.x;
  if (e < N_EDGES) atomicAdd(&deg[dst[e]], 1);
}
__global__ void k_dinv(const int* __restrict__ deg, float* __restrict__ dinv){
  int i = blockIdx.x*blockDim.x+threadIdx.x;
  if (i < N_NODES) dinv[i] = rsqrtf((float)(deg[i]+1));
}
// single-block exclusive prefix scan of deg -> rowptr (N_NODES+1 entries)
__global__ __launch_bounds__(1024) void k_scan(const int* __restrict__ deg, int* __restrict__ rowptr){
  __shared__ int sh[1024];
  int t = threadIdx.x;
  const int C = 20;                 // 1024*20 = 20480 >= 20000
  int base = t*C;
  int loc[C];
  int s = 0;
  #pragma unroll
  for (int i=0;i<C;i++){ int idx=base+i; int v = (idx<N_NODES)?deg[idx]:0; loc[i]=s; s+=v; }
  sh[t]=s; __syncthreads();
  for (int off=1; off<1024; off<<=1){
    int v = (t>=off)?sh[t-off]:0;
    __syncthreads();
    sh[t]+=v;
    __syncthreads();
  }
  int excl = (t==0)?0:sh[t-1];
  #pragma unroll
  for (int i=0;i<C;i++){ int idx=base+i; if(idx<N_NODES) rowptr[idx]=excl+loc[i]; }
  if (t==1023) rowptr[N_NODES]=sh[1023];
}
__global__ void k_copy_i(const int* __restrict__ a, int* __restrict__ b, int n){
  int i = blockIdx.x*blockDim.x+threadIdx.x; if(i<n) b[i]=a[i];
}
__global__ void k_scatter(const int* __restrict__ src, const int* __restrict__ dst,
                          int* __restrict__ cursor, int* __restrict__ colsrc){
  int e = blockIdx.x*blockDim.x+threadIdx.x;
  if (e < N_EDGES){
    int p = atomicAdd(&cursor[dst[e]], 1);
    colsrc[p] = src[e];
  }
}

// ---------------- fp32 tiled GEMM: C[M,N] = A[M,K] @ B[K,N] (+bias) (+relu) ----------------
// 64x64 tile, BK=16, 256 threads, 4x4 micro-tile per thread.
__global__ __launch_bounds__(256) void k_gemm(const float* __restrict__ A, const float* __restrict__ B,
    const float* __restrict__ bias, float* __restrict__ C, int M, int N, int K, int relu)
{
  __shared__ float As[16][64];  // [k][m]
  __shared__ float Bs[16][64];  // [k][n]
  int tid = threadIdx.x;
  int bm = blockIdx.x * 64, bn = blockIdx.y * 64;
  int tm = (tid >> 4) << 2;     // 0..60
  int tn = (tid & 15) << 2;     // 0..60
  float acc[4][4] = {};
  int arow = tid >> 2;          // 0..63
  int akk  = (tid & 3) << 2;    // 0,4,8,12
  int bkrow = tid >> 4;         // 0..15
  int bnn   = (tid & 15) << 2;  // 0..60
  long gmA = (long)(bm + arow) * K;
  bool arow_ok = (bm + arow) < M;

  for (int k0 = 0; k0 < K; k0 += 16) {
    // --- load A tile (64 rows x 16 k) ---
    if (arow_ok && (k0 + akk + 3) < K) {
      float4 v = *(const float4*)&A[gmA + k0 + akk];
      As[akk+0][arow]=v.x; As[akk+1][arow]=v.y; As[akk+2][arow]=v.z; As[akk+3][arow]=v.w;
    } else {
      #pragma unroll
      for (int i=0;i<4;i++){
        int gk = k0+akk+i;
        As[akk+i][arow] = (arow_ok && gk<K) ? A[gmA+gk] : 0.f;
      }
    }
    // --- load B tile (16 k x 64 n) ---
    int gk = k0 + bkrow;
    if (gk < K && (bn + bnn + 3) < N) {
      *(float4*)&Bs[bkrow][bnn] = *(const float4*)&B[(long)gk*N + bn + bnn];
    } else {
      #pragma unroll
      for (int i=0;i<4;i++){
        int gn = bn+bnn+i;
        Bs[bkrow][bnn+i] = (gk<K && gn<N) ? B[(long)gk*N+gn] : 0.f;
      }
    }
    __syncthreads();
    #pragma unroll
    for (int k=0;k<16;k++){
      float a0=As[k][tm+0], a1=As[k][tm+1], a2=As[k][tm+2], a3=As[k][tm+3];
      float b0=Bs[k][tn+0], b1=Bs[k][tn+1], b2=Bs[k][tn+2], b3=Bs[k][tn+3];
      acc[0][0]+=a0*b0; acc[0][1]+=a0*b1; acc[0][2]+=a0*b2; acc[0][3]+=a0*b3;
      acc[1][0]+=a1*b0; acc[1][1]+=a1*b1; acc[1][2]+=a1*b2; acc[1][3]+=a1*b3;
      acc[2][0]+=a2*b0; acc[2][1]+=a2*b1; acc[2][2]+=a2*b2; acc[2][3]+=a2*b3;
      acc[3][0]+=a3*b0; acc[3][1]+=a3*b1; acc[3][2]+=a3*b2; acc[3][3]+=a3*b3;
    }
    __syncthreads();
  }
  // --- epilogue ---
  #pragma unroll
  for (int i=0;i<4;i++){
    int gm = bm+tm+i;
    if (gm >= M) continue;
    if ((bn+tn+3) < N) {
      float4 v;
      float* vp = &v.x;
      #pragma unroll
      for (int j=0;j<4;j++){
        float z = acc[i][j] + (bias ? bias[bn+tn+j] : 0.f);
        vp[j] = relu ? fmaxf(z, 0.f) : z;
      }
      *(float4*)&C[(long)gm*N + bn + tn] = v;
    } else {
      #pragma unroll
      for (int j=0;j<4;j++){
        int gn = bn+tn+j;
        if (gn < N) {
          float z = acc[i][j] + (bias ? bias[gn] : 0.f);
          C[(long)gm*N+gn] = relu ? fmaxf(z, 0.f) : z;
        }
      }
    }
  }
}

// ---------------- GCN aggregation: one block per dst node, 256 thr x 2 channels ----------------
__global__ __launch_bounds__(256) void k_agg(const float* __restrict__ h,
    const int* __restrict__ rowptr, const int* __restrict__ colsrc,
    const float* __restrict__ dinv, const float* __restrict__ bias,
    float* __restrict__ out)
{
  int d = blockIdx.x;
  int c = threadIdx.x;
  float di = dinv[d];
  int beg = rowptr[d], end = rowptr[d+1];
  float acc0 = 0.f, acc1 = 0.f;
  for (int e = beg; e < end; e++) {
    int s = colsrc[e];
    float coef = dinv[s]*di;
    const float* hp = h + (long)s*F_H;
    acc0 += hp[c]*coef;
    acc1 += hp[c+256]*coef;
  }
  const float* hd = h + (long)d*F_H;
  float selfc = di*di;
  acc0 += hd[c]*selfc;
  acc1 += hd[c+256]*selfc;
  out[(long)d*F_H+c]     = acc0 + bias[c];
  out[(long)d*F_H+c+256] = acc1 + bias[c+256];
}

// ---------------- GraphNorm (per-channel stats over all nodes) ----------------
#define STAT_ROWS 50   // 400 blocks x 50 rows = 20000
__global__ __launch_bounds__(512) void k_colsum(const float* __restrict__ x, float* __restrict__ msum){
  int c = threadIdx.x;
  int r0 = blockIdx.x*STAT_ROWS;
  float s = 0.f;
  for (int r=r0;r<r0+STAT_ROWS;r++) s += x[(long)r*F_H+c];
  atomicAdd(&msum[c], s);
}
__global__ __launch_bounds__(512) void k_varsum(const float* __restrict__ x, const float* __restrict__ msum,
    const float* __restrict__ a, float* __restrict__ vsum){
  int c = threadIdx.x;
  float am = a[c]*(msum[c]*(1.f/N_NODES));
  int r0 = blockIdx.x*STAT_ROWS;
  float s = 0.f;
  for (int r=r0;r<r0+STAT_ROWS;r++){ float v = x[(long)r*F_H+c]-am; s += v*v; }
  atomicAdd(&vsum[c], s);
}
// normalize + relu; store layer output; update JK max; optional residual for next conv input
__global__ __launch_bounds__(512) void k_final(const float* __restrict__ x, const float* __restrict__ msum,
    const float* __restrict__ vsum, const float* __restrict__ w, const float* __restrict__ b,
    const float* __restrict__ a, float* __restrict__ lout, float* __restrict__ jk,
    const float* __restrict__ prev, float* __restrict__ hnext, int initjk)
{
  int c = threadIdx.x;
  float mean = msum[c]*(1.f/N_NODES);
  float am = a[c]*mean;
  float inv = rsqrtf(vsum[c]*(1.f/N_NODES)+EPSV);
  float wc = w[c], bc = b[c];
  int r0 = blockIdx.x*STAT_ROWS;
  for (int r=r0;r<r0+STAT_ROWS;r++){
    long idx = (long)r*F_H+c;
    float y = fmaxf(wc*(x[idx]-am)*inv+bc, 0.f);
    lout[idx] = y;
    if (initjk) jk[idx] = y;
    else        jk[idx] = fmaxf(jk[idx], y);
    if (hnext)  hnext[idx] = y + prev[idx];
  }
}

extern "C" void kernel_launch(void* const* d_in, const int* in_sizes, int n_in,
                              void* d_out, int out_size, void* d_ws, size_t ws_size,
                              hipStream_t stream) {
  (void)in_sizes; (void)n_in; (void)out_size; (void)ws_size;
  const float* x     = (const float*)d_in[0];
  const int*   ei    = (const int*)d_in[1];
  const int*   srcp  = ei;            // edge_index[0]
  const int*   dstp  = ei + N_EDGES;  // edge_index[1]
  const float* Wc[3]  = {(const float*)d_in[2], (const float*)d_in[4], (const float*)d_in[6]};
  const float* bc_[3] = {(const float*)d_in[3], (const float*)d_in[5], (const float*)d_in[7]};
  const float* lin1W = (const float*)d_in[8];
  const float* lin1b = (const float*)d_in[9];
  const float* lin2W = (const float*)d_in[10];
  const float* lin2b = (const float*)d_in[11];
  const float* gw[3] = {(const float*)d_in[12], (const float*)d_in[15], (const float*)d_in[18]};
  const float* gb[3] = {(const float*)d_in[13], (const float*)d_in[16], (const float*)d_in[19]};
  const float* ga[3] = {(const float*)d_in[14], (const float*)d_in[17], (const float*)d_in[20]};

  float* out = (float*)d_out;
  const long SZ = (long)N_NODES * F_H;   // 10,240,000 floats
  // d_out (92.88M floats) doubles as scratch; all 5 buffers dead before final GEMM overwrites d_out.
  float* l0  = out;
  float* l1  = out + SZ;
  float* l2  = out + 2*SZ;
  float* jk  = out + 3*SZ;
  float* hin = out + 4*SZ;
  float* louts[3] = {l0, l1, l2};

  // workspace: t(41MB) + agg(41MB) + small arrays (~1.6MB)
  float* t    = (float*)d_ws;
  float* agg  = t + SZ;
  float* dinv = agg + SZ;
  float* msum = dinv + N_NODES;
  float* vsum = msum + F_H;
  int*   deg    = (int*)(vsum + F_H);
  int*   rowptr = deg + N_NODES;
  int*   cursor = rowptr + N_NODES + 1;
  int*   colsrc = cursor + N_NODES;

  // ---- CSR build (degree depends only on dst; shared across layers) ----
  k_zero_i<<<(N_NODES+255)/256,256,0,stream>>>(deg, N_NODES);
  k_degree<<<(N_EDGES+255)/256,256,0,stream>>>(dstp, deg);
  k_dinv<<<(N_NODES+255)/256,256,0,stream>>>(deg, dinv);
  k_scan<<<1,1024,0,stream>>>(deg, rowptr);
  k_copy_i<<<(N_NODES+255)/256,256,0,stream>>>(rowptr, cursor, N_NODES);
  k_scatter<<<(N_EDGES+255)/256,256,0,stream>>>(srcp, dstp, cursor, colsrc);

  // ---- 3 GCN layers ----
  for (int i = 0; i < 3; i++) {
    const float* Ain = (i==0) ? x : ((i==1) ? l0 : hin);
    int K = (i==0) ? F_IN : F_H;
    dim3 g((N_NODES+63)/64, (F_H+63)/64);
    k_gemm<<<g,256,0,stream>>>(Ain, Wc[i], nullptr, t, N_NODES, F_H, K, 0);
    k_agg<<<N_NODES,256,0,stream>>>(t, rowptr, colsrc, dinv, bc_[i], agg);
    k_zero_f<<<4,256,0,stream>>>(msum, 1024);   // msum(512)+vsum(512) contiguous
    k_colsum<<<400,512,0,stream>>>(agg, msum);
    k_varsum<<<400,512,0,stream>>>(agg, msum, ga[i], vsum);
    k_final<<<400,512,0,stream>>>(agg, msum, vsum, gw[i], gb[i], ga[i], louts[i], jk,
                                  (i==1)? l0 : nullptr, (i==1)? hin : nullptr, (i==0)?1:0);
  }

  // ---- head: f1 = relu(jk@lin1_W+b), out = f1@lin2_W+b ----
  {
    dim3 g1((N_NODES+63)/64, (F_H+63)/64);
    k_gemm<<<g1,256,0,stream>>>(jk, lin1W, lin1b, t, N_NODES, F_H, F_H, 1);  // f1 reuses t
    dim3 g2((N_NODES+63)/64, (F_IN+63)/64);
    k_gemm<<<g2,256,0,stream>>>(t, lin2W, lin2b, out, N_NODES, F_IN, F_H, 0);
  }
}

// Round 2
// 1899.515 us; speedup vs baseline: 1.9775x; 1.9775x over previous
//
#include <hip/hip_runtime.h>
#include <hip/hip_bf16.h>

#define N_NODES 20000
#define N_EDGES 320000
#define F_IN 4644
#define F_H 512
#define EPSV 1e-5f

using short8  = __attribute__((ext_vector_type(8))) short;
using f32x4   = __attribute__((ext_vector_type(4))) float;
using ushort4v= __attribute__((ext_vector_type(4))) unsigned short;

// ---------------- utility kernels ----------------
__global__ void k_zero_i(int* p, int n){ int i = blockIdx.x*blockDim.x+threadIdx.x; if(i<n) p[i]=0; }
__global__ void k_zero_f(float* p, int n){ int i = blockIdx.x*blockDim.x+threadIdx.x; if(i<n) p[i]=0.f; }

__global__ void k_degree(const int* __restrict__ dst, int* __restrict__ deg){
  int e = blockIdx.x*blockDim.x+threadIdx.x;
  if (e < N_EDGES) atomicAdd(&deg[dst[e]], 1);
}
__global__ void k_dinv(const int* __restrict__ deg, float* __restrict__ dinv){
  int i = blockIdx.x*blockDim.x+threadIdx.x;
  if (i < N_NODES) dinv[i] = rsqrtf((float)(deg[i]+1));
}
__global__ __launch_bounds__(1024) void k_scan(const int* __restrict__ deg, int* __restrict__ rowptr){
  __shared__ int sh[1024];
  int t = threadIdx.x;
  const int C = 20;
  int base = t*C;
  int loc[C];
  int s = 0;
  #pragma unroll
  for (int i=0;i<C;i++){ int idx=base+i; int v = (idx<N_NODES)?deg[idx]:0; loc[i]=s; s+=v; }
  sh[t]=s; __syncthreads();
  for (int off=1; off<1024; off<<=1){
    int v = (t>=off)?sh[t-off]:0;
    __syncthreads();
    sh[t]+=v;
    __syncthreads();
  }
  int excl = (t==0)?0:sh[t-1];
  #pragma unroll
  for (int i=0;i<C;i++){ int idx=base+i; if(idx<N_NODES) rowptr[idx]=excl+loc[i]; }
  if (t==1023) rowptr[N_NODES]=sh[1023];
}
__global__ void k_copy_i(const int* __restrict__ a, int* __restrict__ b, int n){
  int i = blockIdx.x*blockDim.x+threadIdx.x; if(i<n) b[i]=a[i];
}
__global__ void k_scatter(const int* __restrict__ src, const int* __restrict__ dst,
                          int* __restrict__ cursor, int* __restrict__ colsrc){
  int e = blockIdx.x*blockDim.x+threadIdx.x;
  if (e < N_EDGES){
    int p = atomicAdd(&cursor[dst[e]], 1);
    colsrc[p] = src[e];
  }
}

__device__ inline unsigned short f2b(float f){
  union{float f; unsigned u;} v; v.f=f;
  unsigned u = v.u + 0x7fffu + ((v.u>>16)&1u);
  return (unsigned short)(u>>16);
}

// transpose+convert: B[K][N] fp32 -> BT[NP][KP] bf16 (zero-padded)
__global__ void k_cvtT(const float* __restrict__ B, unsigned short* __restrict__ BT,
                       int K, int N, int NP, int KP){
  int t = blockIdx.x*blockDim.x+threadIdx.x;
  if (t >= NP*KP) return;
  int n = t / KP, k = t % KP;
  float v = (n < N && k < K) ? B[(long)k*N + n] : 0.f;
  BT[t] = f2b(v);
}

// ---------------- bf16 MFMA GEMM: C[M,N] = A[M,K](fp32) @ BT[N,K](bf16)^T ----------------
// 128x128 tile, BK=32, 256 threads = 4 waves (2x2), each wave 64x64 via 4x4 16x16 frags.
__global__ __launch_bounds__(256) void k_gemm_bf16(const float* __restrict__ A,
    const unsigned short* __restrict__ BT, const float* __restrict__ bias,
    float* __restrict__ C, int M, int N, int K, int KP, int lda, int ldc)
{
  __shared__ unsigned short As[128*32];
  __shared__ unsigned short Bs[128*32];
  int tid  = threadIdx.x;
  int bn   = blockIdx.x * 128;   // x = N-blocks: blocks sharing an A-panel run adjacently
  int bm   = blockIdx.y * 128;
  int wave = tid >> 6, lane = tid & 63;
  int wm = (wave & 1) * 64, wn = (wave >> 1) * 64;
  int l15 = lane & 15, l4 = lane >> 4;

  f32x4 acc[4][4];
  #pragma unroll
  for (int m=0;m<4;m++)
    #pragma unroll
    for (int n=0;n<4;n++) acc[m][n] = (f32x4){0.f,0.f,0.f,0.f};

  // A staging map: 4 iters, f=i*256+tid -> row=f/8, quad q=f%8 (4 floats each)
  // B staging map: 2 iters, f=i*256+tid -> row=f/4, oct q=f%4 (8 bf16 each)
  for (int k0 = 0; k0 < KP; k0 += 32) {
    #pragma unroll
    for (int i=0;i<4;i++){
      int f = i*256 + tid;
      int r = f >> 3, q = f & 7;
      int grow = bm + r, gk = k0 + q*4;
      float4 v = make_float4(0.f,0.f,0.f,0.f);
      if (grow < M && gk < K)                        // gk%4==0, K%4==0 -> full float4 in-bounds
        v = *(const float4*)&A[(long)grow*lda + gk];
      ushort4v h;
      h.x = f2b(v.x); h.y = f2b(v.y); h.z = f2b(v.z); h.w = f2b(v.w);
      *(ushort4v*)&As[r*32 + q*4] = h;
    }
    #pragma unroll
    for (int i=0;i<2;i++){
      int f = i*256 + tid;
      int r = f >> 2, q = f & 3;
      short8 bv = *(const short8*)&BT[(long)(bn + r)*KP + k0 + q*8];  // BT padded, always in-bounds
      *(short8*)&Bs[r*32 + q*8] = bv;
    }
    __syncthreads();

    short8 af[4], bf[4];
    #pragma unroll
    for (int m=0;m<4;m++) af[m] = *(const short8*)&As[(wm + m*16 + l15)*32 + l4*8];
    #pragma unroll
    for (int n=0;n<4;n++) bf[n] = *(const short8*)&Bs[(wn + n*16 + l15)*32 + l4*8];
    #pragma unroll
    for (int m=0;m<4;m++)
      #pragma unroll
      for (int n=0;n<4;n++)
        acc[m][n] = __builtin_amdgcn_mfma_f32_16x16x32_bf16(af[m], bf[n], acc[m][n], 0, 0, 0);
    __syncthreads();
  }

  // epilogue: D row = bm+wm+m*16+(lane>>4)*4+r ; col = bn+wn+n*16+(lane&15)
  #pragma unroll
  for (int m=0;m<4;m++){
    #pragma unroll
    for (int n=0;n<4;n++){
      int col = bn + wn + n*16 + l15;
      if (col >= N) continue;
      float bi = bias ? bias[col] : 0.f;
      #pragma unroll
      for (int r=0;r<4;r++){
        int row = bm + wm + m*16 + l4*4 + r;
        if (row < M) C[(long)row*ldc + col] = acc[m][n][r] + bi;
      }
    }
  }
}

// ---------------- fp32 tiled GEMM (kept for HxH layers + fallback) ----------------
__global__ __launch_bounds__(256) void k_gemm(const float* __restrict__ A, const float* __restrict__ B,
    const float* __restrict__ bias, float* __restrict__ C, int M, int N, int K, int relu)
{
  __shared__ float As[16][64];
  __shared__ float Bs[16][64];
  int tid = threadIdx.x;
  int bm = blockIdx.x * 64, bn = blockIdx.y * 64;
  int tm = (tid >> 4) << 2;
  int tn = (tid & 15) << 2;
  float acc[4][4] = {};
  int arow = tid >> 2;
  int akk  = (tid & 3) << 2;
  int bkrow = tid >> 4;
  int bnn   = (tid & 15) << 2;
  long gmA = (long)(bm + arow) * K;
  bool arow_ok = (bm + arow) < M;

  for (int k0 = 0; k0 < K; k0 += 16) {
    if (arow_ok && (k0 + akk + 3) < K) {
      float4 v = *(const float4*)&A[gmA + k0 + akk];
      As[akk+0][arow]=v.x; As[akk+1][arow]=v.y; As[akk+2][arow]=v.z; As[akk+3][arow]=v.w;
    } else {
      #pragma unroll
      for (int i=0;i<4;i++){
        int gk = k0+akk+i;
        As[akk+i][arow] = (arow_ok && gk<K) ? A[gmA+gk] : 0.f;
      }
    }
    int gk = k0 + bkrow;
    if (gk < K && (bn + bnn + 3) < N) {
      *(float4*)&Bs[bkrow][bnn] = *(const float4*)&B[(long)gk*N + bn + bnn];
    } else {
      #pragma unroll
      for (int i=0;i<4;i++){
        int gn = bn+bnn+i;
        Bs[bkrow][bnn+i] = (gk<K && gn<N) ? B[(long)gk*N+gn] : 0.f;
      }
    }
    __syncthreads();
    #pragma unroll
    for (int k=0;k<16;k++){
      float a0=As[k][tm+0], a1=As[k][tm+1], a2=As[k][tm+2], a3=As[k][tm+3];
      float b0=Bs[k][tn+0], b1=Bs[k][tn+1], b2=Bs[k][tn+2], b3=Bs[k][tn+3];
      acc[0][0]+=a0*b0; acc[0][1]+=a0*b1; acc[0][2]+=a0*b2; acc[0][3]+=a0*b3;
      acc[1][0]+=a1*b0; acc[1][1]+=a1*b1; acc[1][2]+=a1*b2; acc[1][3]+=a1*b3;
      acc[2][0]+=a2*b0; acc[2][1]+=a2*b1; acc[2][2]+=a2*b2; acc[2][3]+=a2*b3;
      acc[3][0]+=a3*b0; acc[3][1]+=a3*b1; acc[3][2]+=a3*b2; acc[3][3]+=a3*b3;
    }
    __syncthreads();
  }
  #pragma unroll
  for (int i=0;i<4;i++){
    int gm = bm+tm+i;
    if (gm >= M) continue;
    #pragma unroll
    for (int j=0;j<4;j++){
      int gn = bn+tn+j;
      if (gn < N) {
        float z = acc[i][j] + (bias ? bias[gn] : 0.f);
        C[(long)gm*N+gn] = relu ? fmaxf(z, 0.f) : z;
      }
    }
  }
}

// ---------------- GCN aggregation ----------------
__global__ __launch_bounds__(256) void k_agg(const float* __restrict__ h,
    const int* __restrict__ rowptr, const int* __restrict__ colsrc,
    const float* __restrict__ dinv, const float* __restrict__ bias,
    float* __restrict__ out)
{
  int d = blockIdx.x;
  int c = threadIdx.x;
  float di = dinv[d];
  int beg = rowptr[d], end = rowptr[d+1];
  float acc0 = 0.f, acc1 = 0.f;
  for (int e = beg; e < end; e++) {
    int s = colsrc[e];
    float coef = dinv[s]*di;
    const float* hp = h + (long)s*F_H;
    acc0 += hp[c]*coef;
    acc1 += hp[c+256]*coef;
  }
  const float* hd = h + (long)d*F_H;
  float selfc = di*di;
  acc0 += hd[c]*selfc;
  acc1 += hd[c+256]*selfc;
  out[(long)d*F_H+c]     = acc0 + bias[c];
  out[(long)d*F_H+c+256] = acc1 + bias[c+256];
}

// ---------------- GraphNorm ----------------
#define STAT_ROWS 50
__global__ __launch_bounds__(512) void k_colsum(const float* __restrict__ x, float* __restrict__ msum){
  int c = threadIdx.x;
  int r0 = blockIdx.x*STAT_ROWS;
  float s = 0.f;
  for (int r=r0;r<r0+STAT_ROWS;r++) s += x[(long)r*F_H+c];
  atomicAdd(&msum[c], s);
}
__global__ __launch_bounds__(512) void k_varsum(const float* __restrict__ x, const float* __restrict__ msum,
    const float* __restrict__ a, float* __restrict__ vsum){
  int c = threadIdx.x;
  float am = a[c]*(msum[c]*(1.f/N_NODES));
  int r0 = blockIdx.x*STAT_ROWS;
  float s = 0.f;
  for (int r=r0;r<r0+STAT_ROWS;r++){ float v = x[(long)r*F_H+c]-am; s += v*v; }
  atomicAdd(&vsum[c], s);
}
__global__ __launch_bounds__(512) void k_final(const float* __restrict__ x, const float* __restrict__ msum,
    const float* __restrict__ vsum, const float* __restrict__ w, const float* __restrict__ b,
    const float* __restrict__ a, float* __restrict__ lout, float* __restrict__ jk,
    const float* __restrict__ prev, float* __restrict__ hnext, int initjk)
{
  int c = threadIdx.x;
  float mean = msum[c]*(1.f/N_NODES);
  float am = a[c]*mean;
  float inv = rsqrtf(vsum[c]*(1.f/N_NODES)+EPSV);
  float wc = w[c], bc = b[c];
  int r0 = blockIdx.x*STAT_ROWS;
  for (int r=r0;r<r0+STAT_ROWS;r++){
    long idx = (long)r*F_H+c;
    float y = fmaxf(wc*(x[idx]-am)*inv+bc, 0.f);
    lout[idx] = y;
    if (initjk) jk[idx] = y;
    else        jk[idx] = fmaxf(jk[idx], y);
    if (hnext)  hnext[idx] = y + prev[idx];
  }
}

extern "C" void kernel_launch(void* const* d_in, const int* in_sizes, int n_in,
                              void* d_out, int out_size, void* d_ws, size_t ws_size,
                              hipStream_t stream) {
  (void)in_sizes; (void)n_in; (void)out_size;
  const float* x     = (const float*)d_in[0];
  const int*   ei    = (const int*)d_in[1];
  const int*   srcp  = ei;
  const int*   dstp  = ei + N_EDGES;
  const float* Wc[3]  = {(const float*)d_in[2], (const float*)d_in[4], (const float*)d_in[6]};
  const float* bc_[3] = {(const float*)d_in[3], (const float*)d_in[5], (const float*)d_in[7]};
  const float* lin1W = (const float*)d_in[8];
  const float* lin1b = (const float*)d_in[9];
  const float* lin2W = (const float*)d_in[10];
  const float* lin2b = (const float*)d_in[11];
  const float* gw[3] = {(const float*)d_in[12], (const float*)d_in[15], (const float*)d_in[18]};
  const float* gb[3] = {(const float*)d_in[13], (const float*)d_in[16], (const float*)d_in[19]};
  const float* ga[3] = {(const float*)d_in[14], (const float*)d_in[17], (const float*)d_in[20]};

  float* out = (float*)d_out;
  const long SZ = (long)N_NODES * F_H;
  float* l0  = out;
  float* l1  = out + SZ;
  float* l2  = out + 2*SZ;
  float* jk  = out + 3*SZ;
  float* hin = out + 4*SZ;
  float* louts[3] = {l0, l1, l2};

  // ---- workspace layout ----
  float* ws   = (float*)d_ws;
  float* t    = ws;                         // SZ
  float* agg  = t + SZ;                     // SZ
  float* dinv = agg + SZ;                   // 20000
  float* msum = dinv + N_NODES;             // 512
  float* vsum = msum + F_H;                 // 512
  int*   deg    = (int*)(vsum + F_H);       // 20000
  int*   rowptr = deg + N_NODES;            // 20001
  int*   cursor = rowptr + N_NODES + 1;     // 20000
  int*   colsrc = cursor + N_NODES;         // 320000
  long smallEnd = 2*SZ + N_NODES + 2*F_H + (3*N_NODES + 1 + N_EDGES); // in floats (int==float size)
  smallEnd = (smallEnd + 3) & ~3L;          // 16B align
  const int KP0 = 4672;                     // F_IN padded to 32
  const int NP2 = 4736;                     // F_IN padded to 128
  unsigned short* W0T  = (unsigned short*)(ws + smallEnd);          // [512][4672]
  long w0tF = ((long)F_H * KP0 + 1) / 2;
  unsigned short* l2WT = (unsigned short*)(ws + smallEnd + w0tF);   // [4736][512]
  long l2wF = ((long)NP2 * F_H + 1) / 2;
  size_t wsNeed = (size_t)(smallEnd + w0tF + l2wF) * 4;
  bool useMfma = (ws_size >= wsNeed + 64);

  // ---- CSR build ----
  k_zero_i<<<(N_NODES+255)/256,256,0,stream>>>(deg, N_NODES);
  k_degree<<<(N_EDGES+255)/256,256,0,stream>>>(dstp, deg);
  k_dinv<<<(N_NODES+255)/256,256,0,stream>>>(deg, dinv);
  k_scan<<<1,1024,0,stream>>>(deg, rowptr);
  k_copy_i<<<(N_NODES+255)/256,256,0,stream>>>(rowptr, cursor, N_NODES);
  k_scatter<<<(N_EDGES+255)/256,256,0,stream>>>(srcp, dstp, cursor, colsrc);

  if (useMfma) {
    int nW0 = F_H*KP0;
    k_cvtT<<<(nW0+255)/256,256,0,stream>>>(Wc[0], W0T, F_IN, F_H, F_H, KP0);
  }

  // ---- 3 GCN layers ----
  for (int i = 0; i < 3; i++) {
    const float* Ain = (i==0) ? x : ((i==1) ? l0 : hin);
    int K = (i==0) ? F_IN : F_H;
    if (i == 0 && useMfma) {
      dim3 g(F_H/128, (N_NODES+127)/128);   // x = N-blocks (A-panel L2 reuse)
      k_gemm_bf16<<<g,256,0,stream>>>(x, W0T, nullptr, t, N_NODES, F_H, F_IN, KP0, F_IN, F_H);
    } else {
      dim3 g((N_NODES+63)/64, (F_H+63)/64);
      k_gemm<<<g,256,0,stream>>>(Ain, Wc[i], nullptr, t, N_NODES, F_H, K, 0);
    }
    k_agg<<<N_NODES,256,0,stream>>>(t, rowptr, colsrc, dinv, bc_[i], agg);
    k_zero_f<<<4,256,0,stream>>>(msum, 1024);
    k_colsum<<<400,512,0,stream>>>(agg, msum);
    k_varsum<<<400,512,0,stream>>>(agg, msum, ga[i], vsum);
    k_final<<<400,512,0,stream>>>(agg, msum, vsum, gw[i], gb[i], ga[i], louts[i], jk,
                                  (i==1)? l0 : nullptr, (i==1)? hin : nullptr, (i==0)?1:0);
  }

  // ---- head ----
  {
    dim3 g1((N_NODES+63)/64, (F_H+63)/64);
    k_gemm<<<g1,256,0,stream>>>(jk, lin1W, lin1b, t, N_NODES, F_H, F_H, 1);  // f1 -> t (fp32)
    if (useMfma) {
      int nW2 = NP2*F_H;
      k_cvtT<<<(nW2+255)/256,256,0,stream>>>(lin2W, l2WT, F_H, F_IN, NP2, F_H);
      dim3 g2(NP2/128, (N_NODES+127)/128);
      k_gemm_bf16<<<g2,256,0,stream>>>(t, l2WT, lin2b, out, N_NODES, F_IN, F_H, F_H, F_H, F_IN);
    } else {
      dim3 g2((N_NODES+63)/64, (F_IN+63)/64);
      k_gemm<<<g2,256,0,stream>>>(t, lin2W, lin2b, out, N_NODES, F_IN, F_H, 0);
    }
  }
}

// Round 4
// 1130.205 us; speedup vs baseline: 3.3236x; 1.6807x over previous
//
#include <hip/hip_runtime.h>

#define N_NODES 20000
#define N_PAD   20096      /* 157*128 */
#define N_EDGES 320000
#define F_IN 4644
#define KP0  4672          /* F_IN padded to 32 */
#define NP2  4736          /* F_IN padded to 128 */
#define F_H 512
#define EPSV 1e-5f
#define SZL 10240000L      /* N_NODES*F_H floats */
#define ACT 5200000L       /* floats per bf16 activation buffer: >= N_PAD*F_H/2 = 5,144,576 */

using short8 = __attribute__((ext_vector_type(8))) short;
using f32x4  = __attribute__((ext_vector_type(4))) float;

__device__ inline unsigned short f2b(float f){
  union{float f; unsigned u;} v; v.f=f;
  unsigned u = v.u + 0x7fffu + ((v.u>>16)&1u);
  return (unsigned short)(u>>16);
}
__device__ inline float blo(unsigned v){ return __uint_as_float(v<<16); }
__device__ inline float bhi(unsigned v){ return __uint_as_float(v & 0xffff0000u); }

#define GLDS(g, l) __builtin_amdgcn_global_load_lds( \
    (const __attribute__((address_space(1))) void*)(g), \
    (__attribute__((address_space(3))) void*)(l), 16, 0, 0)

// ---------------- utility / CSR ----------------
__global__ void k_zero_i(int* p, int n){ int i = blockIdx.x*blockDim.x+threadIdx.x; if(i<n) p[i]=0; }
__global__ void k_zero_f(float* p, int n){ int i = blockIdx.x*blockDim.x+threadIdx.x; if(i<n) p[i]=0.f; }

__global__ void k_degree(const int* __restrict__ dst, int* __restrict__ deg){
  int e = blockIdx.x*blockDim.x+threadIdx.x;
  if (e < N_EDGES) atomicAdd(&deg[dst[e]], 1);
}
__global__ void k_dinv(const int* __restrict__ deg, float* __restrict__ dinv){
  int i = blockIdx.x*blockDim.x+threadIdx.x;
  if (i < N_NODES) dinv[i] = rsqrtf((float)(deg[i]+1));
}
__global__ __launch_bounds__(1024) void k_scan(const int* __restrict__ deg, int* __restrict__ rowptr){
  __shared__ int sh[1024];
  int t = threadIdx.x;
  const int C = 20;
  int base = t*C;
  int loc[C];
  int s = 0;
  #pragma unroll
  for (int i=0;i<C;i++){ int idx=base+i; int v = (idx<N_NODES)?deg[idx]:0; loc[i]=s; s+=v; }
  sh[t]=s; __syncthreads();
  for (int off=1; off<1024; off<<=1){
    int v = (t>=off)?sh[t-off]:0;
    __syncthreads();
    sh[t]+=v;
    __syncthreads();
  }
  int excl = (t==0)?0:sh[t-1];
  #pragma unroll
  for (int i=0;i<C;i++){ int idx=base+i; if(idx<N_NODES) rowptr[idx]=excl+loc[i]; }
  if (t==1023) rowptr[N_NODES]=sh[1023];
}
__global__ void k_copy_i(const int* __restrict__ a, int* __restrict__ b, int n){
  int i = blockIdx.x*blockDim.x+threadIdx.x; if(i<n) b[i]=a[i];
}
__global__ void k_scatter(const int* __restrict__ src, const int* __restrict__ dst,
                          int* __restrict__ cursor, int* __restrict__ colsrc){
  int e = blockIdx.x*blockDim.x+threadIdx.x;
  if (e < N_EDGES){
    int p = atomicAdd(&cursor[dst[e]], 1);
    colsrc[p] = src[e];
  }
}

// ---------------- conversions ----------------
__global__ void k_cvtT(const float* __restrict__ B, unsigned short* __restrict__ BT,
                       int K, int N, int NP, int KP){
  int t = blockIdx.x*blockDim.x+threadIdx.x;
  if (t >= NP*KP) return;
  int n = t / KP, k = t % KP;
  float v = (n < N && k < K) ? B[(long)k*N + n] : 0.f;
  BT[t] = f2b(v);
}
__global__ void k_cvt_x(const float* __restrict__ x, unsigned short* __restrict__ xb){
  long id = (long)blockIdx.x*256 + threadIdx.x;   // one 8-col chunk
  const int CPR = KP0/8;
  if (id >= (long)N_PAD*CPR) return;
  int row = (int)(id / CPR), c8 = (int)(id % CPR);
  int col = c8*8;
  short8 o;
  if (row < N_NODES && col + 8 <= F_IN) {
    const float* p = &x[(long)row*F_IN + col];
    float4 v0 = *(const float4*)p, v1 = *(const float4*)(p+4);
    o[0]=(short)f2b(v0.x); o[1]=(short)f2b(v0.y); o[2]=(short)f2b(v0.z); o[3]=(short)f2b(v0.w);
    o[4]=(short)f2b(v1.x); o[5]=(short)f2b(v1.y); o[6]=(short)f2b(v1.z); o[7]=(short)f2b(v1.w);
  } else {
    #pragma unroll
    for (int j=0;j<8;j++){
      int cc = col+j;
      float v = (row < N_NODES && cc < F_IN) ? x[(long)row*F_IN + cc] : 0.f;
      o[j] = (short)f2b(v);
    }
  }
  *(short8*)&xb[id*8] = o;
}
__global__ void k_red(const float* __restrict__ p0, const float* __restrict__ p1,
                      unsigned short* __restrict__ tb){
  long i = ((long)blockIdx.x*256 + threadIdx.x)*4;
  if (i >= SZL) return;
  float4 a = *(const float4*)&p0[i];
  float4 b = *(const float4*)&p1[i];
  unsigned short o[4] = { f2b(a.x+b.x), f2b(a.y+b.y), f2b(a.z+b.z), f2b(a.w+b.w) };
  *(uint2*)&tb[i] = *(uint2*)o;
}

// ---------------- bf16 MFMA GEMM, global_load_lds staging ----------------
// C[M,N] = A[M,K]@BT[N,K]^T. A,BT bf16 row-major; A must have >= gridDim.y*128 readable rows.
// 128x128 tile, BK=32, 4 waves (2x2), 4x4 16x16x32 frags/wave. gridDim.z = split-K slices.
template<int OUTB, int RELU>
__global__ __launch_bounds__(256) void k_gb(
    const unsigned short* __restrict__ A, const unsigned short* __restrict__ BT,
    const float* __restrict__ bias, void* __restrict__ Cvoid,
    int M, int N, int KP, int lda, int ldc, int kchunk, long zstride)
{
  __shared__ unsigned short As[128*32];
  __shared__ unsigned short Bs[128*32];
  const int tid  = threadIdx.x;
  const int bn   = blockIdx.x * 128;
  const int bm   = blockIdx.y * 128;
  const int z    = blockIdx.z;
  const int wave = tid >> 6, lane = tid & 63;
  const int wm = (wave & 1) * 64, wn = (wave >> 1) * 64;
  const int l15 = lane & 15, l4 = lane >> 4;
  const int k0beg = z * kchunk;
  const int kend0 = k0beg + kchunk;
  const int k0end = (kend0 < KP) ? kend0 : KP;

  f32x4 acc[4][4];
  #pragma unroll
  for (int m=0;m<4;m++)
    #pragma unroll
    for (int n=0;n<4;n++) acc[m][n] = (f32x4){0.f,0.f,0.f,0.f};

  // 16B chunks: tile = 512 chunks = 128 rows x 4; chunk c -> row c>>2, k-slot c&3
  const int c0 = wave*64 + lane;
  const int c1 = c0 + 256;
  const long ar0 = bm + (c0 >> 2); const int as0 = (c0 & 3)*8;
  const long ar1 = bm + (c1 >> 2); const int as1 = (c1 & 3)*8;
  const long br0 = bn + (c0 >> 2);
  const long br1 = bn + (c1 >> 2);
  unsigned short* Ald0 = As + (long)(wave*64)*8;        // wave-uniform base; HW adds lane*16B
  unsigned short* Ald1 = As + (long)(256 + wave*64)*8;
  unsigned short* Bld0 = Bs + (long)(wave*64)*8;
  unsigned short* Bld1 = Bs + (long)(256 + wave*64)*8;

  for (int k0 = k0beg; k0 < k0end; k0 += 32) {
    GLDS(A + ar0*lda + (k0 + as0), Ald0);
    GLDS(A + ar1*lda + (k0 + as1), Ald1);
    GLDS(BT + br0*KP + (k0 + as0), Bld0);
    GLDS(BT + br1*KP + (k0 + as1), Bld1);
    __syncthreads();

    short8 af[4], bf[4];
    #pragma unroll
    for (int m=0;m<4;m++) af[m] = *(const short8*)&As[(wm + m*16 + l15)*32 + l4*8];
    #pragma unroll
    for (int n=0;n<4;n++) bf[n] = *(const short8*)&Bs[(wn + n*16 + l15)*32 + l4*8];
    #pragma unroll
    for (int m=0;m<4;m++)
      #pragma unroll
      for (int n=0;n<4;n++)
        acc[m][n] = __builtin_amdgcn_mfma_f32_16x16x32_bf16(af[m], bf[n], acc[m][n], 0, 0, 0);
    __syncthreads();
  }

  // epilogue: row = bm+wm+m*16+l4*4+r, col = bn+wn+n*16+l15
  #pragma unroll
  for (int m=0;m<4;m++){
    #pragma unroll
    for (int n=0;n<4;n++){
      int col = bn + wn + n*16 + l15;
      if (col >= N) continue;
      float bi = bias ? bias[col] : 0.f;
      #pragma unroll
      for (int r=0;r<4;r++){
        int row = bm + wm + m*16 + l4*4 + r;
        if (row >= M) continue;
        float v = acc[m][n][r] + bi;
        if (RELU) v = fmaxf(v, 0.f);
        if (OUTB) ((unsigned short*)Cvoid)[(long)row*ldc + col] = f2b(v);
        else      (((float*)Cvoid) + z*zstride)[(long)row*ldc + col] = v;
      }
    }
  }
}

// ---------------- GCN aggregation (bf16 h, fp32 accumulate) ----------------
__global__ __launch_bounds__(256) void k_agg(const unsigned short* __restrict__ h,
    const int* __restrict__ rowptr, const int* __restrict__ colsrc,
    const float* __restrict__ dinv, const float* __restrict__ bias,
    float* __restrict__ out)
{
  int d = blockIdx.x;
  int t = threadIdx.x;                 // channel pair 2t,2t+1
  const unsigned* h32 = (const unsigned*)h;
  float di = dinv[d];
  int beg = rowptr[d], end = rowptr[d+1];
  float a0 = 0.f, a1 = 0.f;
  for (int e = beg; e < end; e++) {
    int s = colsrc[e];
    float cf = dinv[s]*di;
    unsigned v = h32[(long)s*256 + t];
    a0 += blo(v)*cf;
    a1 += bhi(v)*cf;
  }
  unsigned v = h32[(long)d*256 + t];
  float sc = di*di;
  a0 += blo(v)*sc;
  a1 += bhi(v)*sc;
  float2 o; o.x = a0 + bias[2*t]; o.y = a1 + bias[2*t+1];
  *(float2*)&out[(long)d*F_H + 2*t] = o;
}

// ---------------- GraphNorm: fused sum+sumsq, then normalize ----------------
#define STAT_ROWS 50
__global__ __launch_bounds__(512) void k_stats(const float* __restrict__ x,
    float* __restrict__ msum, float* __restrict__ ssum){
  int c = threadIdx.x;
  int r0 = blockIdx.x*STAT_ROWS;
  float s = 0.f, s2 = 0.f;
  for (int r=r0;r<r0+STAT_ROWS;r++){ float v = x[(long)r*F_H+c]; s += v; s2 += v*v; }
  atomicAdd(&msum[c], s);
  atomicAdd(&ssum[c], s2);
}
// mode 0: l0f=y, l0b=bf16(y), jkb=bf16(y); mode 1: loutb=bf16(y+l0f), jkb=max; mode 2: jkb=max
__global__ __launch_bounds__(512) void k_final(const float* __restrict__ x,
    const float* __restrict__ msum, const float* __restrict__ ssum,
    const float* __restrict__ w, const float* __restrict__ b, const float* __restrict__ a,
    float* __restrict__ l0f, unsigned short* __restrict__ loutb,
    unsigned short* __restrict__ jkb, int mode)
{
  int c = threadIdx.x;
  float mean = msum[c]*(1.f/N_NODES);
  float aa = a[c];
  float var = ssum[c]*(1.f/N_NODES) - mean*mean*aa*(2.f-aa);
  float inv = rsqrtf(var + EPSV);
  float am = aa*mean;
  float wc = w[c], bc = b[c];
  int r0 = blockIdx.x*STAT_ROWS;
  for (int r=r0;r<r0+STAT_ROWS;r++){
    long idx = (long)r*F_H+c;
    float y = fmaxf(wc*(x[idx]-am)*inv+bc, 0.f);
    if (mode == 0) {
      l0f[idx] = y;
      unsigned short q = f2b(y);
      loutb[idx] = q;
      jkb[idx] = q;
    } else if (mode == 1) {
      loutb[idx] = f2b(y + l0f[idx]);
      float cur = __uint_as_float(((unsigned)jkb[idx])<<16);
      jkb[idx] = f2b(fmaxf(cur, y));
    } else {
      float cur = __uint_as_float(((unsigned)jkb[idx])<<16);
      jkb[idx] = f2b(fmaxf(cur, y));
    }
  }
}

extern "C" void kernel_launch(void* const* d_in, const int* in_sizes, int n_in,
                              void* d_out, int out_size, void* d_ws, size_t ws_size,
                              hipStream_t stream) {
  (void)in_sizes; (void)n_in; (void)out_size; (void)ws_size;
  const float* x     = (const float*)d_in[0];
  const int*   ei    = (const int*)d_in[1];
  const int*   srcp  = ei;
  const int*   dstp  = ei + N_EDGES;
  const float* Wc[3]  = {(const float*)d_in[2], (const float*)d_in[4], (const float*)d_in[6]};
  const float* bc_[3] = {(const float*)d_in[3], (const float*)d_in[5], (const float*)d_in[7]};
  const float* lin1W = (const float*)d_in[8];
  const float* lin1b = (const float*)d_in[9];
  const float* lin2W = (const float*)d_in[10];
  const float* lin2b = (const float*)d_in[11];
  const float* gw[3] = {(const float*)d_in[12], (const float*)d_in[15], (const float*)d_in[18]};
  const float* gb[3] = {(const float*)d_in[13], (const float*)d_in[16], (const float*)d_in[19]};
  const float* ga[3] = {(const float*)d_in[14], (const float*)d_in[17], (const float*)d_in[20]};

  float* out = (float*)d_out;   // out_size = 92,880,000 floats

  // ---- d_out scratch layout (explicit, non-overlapping in time) ----
  // l0  (fp32): [0, 10.24M)
  // xb  (bf16): [10.24M, 57.19M)  -- live only from k_cvt_x to end of conv0 GEMM
  // after conv0 GEMM, the xb region is recycled as four ACT-sized bf16 buffers:
  //   l0b  [10.24M, 15.44M)   hinb [15.44M, 20.64M)   jkb [20.64M, 25.84M)   t_b [25.84M, 31.04M)
  // p1 (fp32): [57.20M, 67.44M)
  float* l0 = out;
  unsigned short* xb   = (unsigned short*)(out + SZL);
  unsigned short* l0b  = (unsigned short*)(out + SZL);
  unsigned short* hinb = (unsigned short*)(out + SZL + ACT);
  unsigned short* jkb  = (unsigned short*)(out + SZL + 2*ACT);
  unsigned short* t_b  = (unsigned short*)(out + SZL + 3*ACT);
  float* p1            = out + 57200000L;

  // ---- ws layout (~74.6 MB) ----
  float* ws   = (float*)d_ws;
  float* p0   = ws;                         // conv0 partial z=0; reused as `agg` afterwards
  float* agg  = ws;
  unsigned short* f1b = (unsigned short*)(ws + SZL);            // lin1 out: ACT floats
  long off = SZL + ACT;
  unsigned short* W0T   = (unsigned short*)(ws + off); off += (long)F_H*KP0/2;   // 1,196,032
  unsigned short* W1T   = (unsigned short*)(ws + off); off += (long)F_H*F_H/2;   // 131,072
  unsigned short* W2T   = (unsigned short*)(ws + off); off += (long)F_H*F_H/2;
  unsigned short* l1WT  = (unsigned short*)(ws + off); off += (long)F_H*F_H/2;
  unsigned short* l2WT  = (unsigned short*)(ws + off); off += (long)NP2*F_H/2;   // 1,212,416
  float* dinv = ws + off;                   off += N_NODES;
  float* msum = ws + off;                   off += F_H;
  float* ssum = ws + off;                   off += F_H;
  int* deg    = (int*)(ws + off);           off += N_NODES;
  int* rowptr = (int*)(ws + off);           off += N_NODES + 1;
  int* cursor = (int*)(ws + off);           off += N_NODES;
  int* colsrc = (int*)(ws + off);           // +320,000 -> total ~18.65M floats

  // ---- CSR build ----
  k_zero_i<<<(N_NODES+255)/256,256,0,stream>>>(deg, N_NODES);
  k_degree<<<(N_EDGES+255)/256,256,0,stream>>>(dstp, deg);
  k_dinv<<<(N_NODES+255)/256,256,0,stream>>>(deg, dinv);
  k_scan<<<1,1024,0,stream>>>(deg, rowptr);
  k_copy_i<<<(N_NODES+255)/256,256,0,stream>>>(rowptr, cursor, N_NODES);
  k_scatter<<<(N_EDGES+255)/256,256,0,stream>>>(srcp, dstp, cursor, colsrc);

  // ---- conversions ----
  {
    long nx = (long)N_PAD*(KP0/8);
    k_cvt_x<<<(int)((nx+255)/256),256,0,stream>>>(x, xb);
    int n0 = F_H*KP0;   k_cvtT<<<(n0+255)/256,256,0,stream>>>(Wc[0], W0T, F_IN, F_H, F_H, KP0);
    int nh = F_H*F_H;   k_cvtT<<<(nh+255)/256,256,0,stream>>>(Wc[1], W1T, F_H, F_H, F_H, F_H);
                        k_cvtT<<<(nh+255)/256,256,0,stream>>>(Wc[2], W2T, F_H, F_H, F_H, F_H);
                        k_cvtT<<<(nh+255)/256,256,0,stream>>>(lin1W, l1WT, F_H, F_H, F_H, F_H);
    int n2 = NP2*F_H;   k_cvtT<<<(n2+255)/256,256,0,stream>>>(lin2W, l2WT, F_H, F_IN, NP2, F_H);
  }

  // ---- 3 GCN layers ----
  for (int i = 0; i < 3; i++) {
    if (i == 0) {
      // split-K=2: z=0 -> p0 (ws), z=1 -> p1 (d_out); zstride maps p0+zstride == p1
      long zs = p1 - p0;
      k_gb<0,0><<<dim3(F_H/128, N_PAD/128, 2),256,0,stream>>>(xb, W0T, nullptr, p0,
          N_NODES, F_H, KP0, KP0, F_H, KP0/2, zs);
      k_red<<<(int)((SZL/4+255)/256),256,0,stream>>>(p0, p1, t_b);   // xb dead by now
    } else {
      const unsigned short* Ain = (i==1) ? l0b : hinb;
      const unsigned short* Wt  = (i==1) ? W1T : W2T;
      k_gb<1,0><<<dim3(F_H/128, N_PAD/128, 1),256,0,stream>>>(Ain, Wt, nullptr, t_b,
          N_NODES, F_H, F_H, F_H, F_H, F_H, 0L);
    }
    k_agg<<<N_NODES,256,0,stream>>>(t_b, rowptr, colsrc, dinv, bc_[i], agg);
    k_zero_f<<<4,256,0,stream>>>(msum, 1024);   // msum+ssum contiguous
    k_stats<<<N_NODES/STAT_ROWS,512,0,stream>>>(agg, msum, ssum);
    k_final<<<N_NODES/STAT_ROWS,512,0,stream>>>(agg, msum, ssum, gw[i], gb[i], ga[i],
        l0, (i==0)? l0b : hinb, jkb, i);
  }

  // ---- head ----
  k_gb<1,1><<<dim3(F_H/128, N_PAD/128, 1),256,0,stream>>>(jkb, l1WT, lin1b, f1b,
      N_NODES, F_H, F_H, F_H, F_H, F_H, 0L);
  k_gb<0,0><<<dim3(NP2/128, N_PAD/128, 1),256,0,stream>>>(f1b, l2WT, lin2b, out,
      N_NODES, F_IN, F_H, F_H, F_IN, F_H, 0L);
}

// Round 5
// 1097.834 us; speedup vs baseline: 3.4216x; 1.0295x over previous
//
#include <hip/hip_runtime.h>

#define N_NODES 20000
#define N_PAD   20096      /* 157*128 */
#define N_EDGES 320000
#define F_IN 4644
#define KP0  4672          /* F_IN padded to 32 */
#define NP2  4736          /* F_IN padded to 128 */
#define F_H 512
#define EPSV 1e-5f
#define SZL 10240000L      /* N_NODES*F_H floats */
#define ACT 5200000L       /* floats per bf16 activation buffer: >= N_PAD*F_H/2 = 5,144,576 */

using short8 = __attribute__((ext_vector_type(8))) short;
using f32x4  = __attribute__((ext_vector_type(4))) float;

__device__ inline unsigned short f2b(float f){
  union{float f; unsigned u;} v; v.f=f;
  unsigned u = v.u + 0x7fffu + ((v.u>>16)&1u);
  return (unsigned short)(u>>16);
}
__device__ inline float blo(unsigned v){ return __uint_as_float(v<<16); }
__device__ inline float bhi(unsigned v){ return __uint_as_float(v & 0xffff0000u); }

#define GLDS(g, l) __builtin_amdgcn_global_load_lds( \
    (const __attribute__((address_space(1))) void*)(g), \
    (__attribute__((address_space(3))) void*)(l), 16, 0, 0)

// ---------------- utility / CSR ----------------
__global__ void k_zero_i(int* p, int n){ int i = blockIdx.x*blockDim.x+threadIdx.x; if(i<n) p[i]=0; }
__global__ void k_zero_f(float* p, int n){ int i = blockIdx.x*blockDim.x+threadIdx.x; if(i<n) p[i]=0.f; }

__global__ void k_degree(const int* __restrict__ dst, int* __restrict__ deg){
  int e = blockIdx.x*blockDim.x+threadIdx.x;
  if (e < N_EDGES) atomicAdd(&deg[dst[e]], 1);
}
__global__ void k_dinv(const int* __restrict__ deg, float* __restrict__ dinv){
  int i = blockIdx.x*blockDim.x+threadIdx.x;
  if (i < N_NODES) dinv[i] = rsqrtf((float)(deg[i]+1));
}
__global__ __launch_bounds__(1024) void k_scan(const int* __restrict__ deg, int* __restrict__ rowptr){
  __shared__ int sh[1024];
  int t = threadIdx.x;
  const int C = 20;
  int base = t*C;
  int loc[C];
  int s = 0;
  #pragma unroll
  for (int i=0;i<C;i++){ int idx=base+i; int v = (idx<N_NODES)?deg[idx]:0; loc[i]=s; s+=v; }
  sh[t]=s; __syncthreads();
  for (int off=1; off<1024; off<<=1){
    int v = (t>=off)?sh[t-off]:0;
    __syncthreads();
    sh[t]+=v;
    __syncthreads();
  }
  int excl = (t==0)?0:sh[t-1];
  #pragma unroll
  for (int i=0;i<C;i++){ int idx=base+i; if(idx<N_NODES) rowptr[idx]=excl+loc[i]; }
  if (t==1023) rowptr[N_NODES]=sh[1023];
}
__global__ void k_copy_i(const int* __restrict__ a, int* __restrict__ b, int n){
  int i = blockIdx.x*blockDim.x+threadIdx.x; if(i<n) b[i]=a[i];
}
__global__ void k_scatter(const int* __restrict__ src, const int* __restrict__ dst,
                          int* __restrict__ cursor, int* __restrict__ colsrc){
  int e = blockIdx.x*blockDim.x+threadIdx.x;
  if (e < N_EDGES){
    int p = atomicAdd(&cursor[dst[e]], 1);
    colsrc[p] = src[e];
  }
}

// ---------------- conversions ----------------
__global__ void k_cvtT(const float* __restrict__ B, unsigned short* __restrict__ BT,
                       int K, int N, int NP, int KP){
  int t = blockIdx.x*blockDim.x+threadIdx.x;
  if (t >= NP*KP) return;
  int n = t / KP, k = t % KP;
  float v = (n < N && k < K) ? B[(long)k*N + n] : 0.f;
  BT[t] = f2b(v);
}
__global__ void k_cvt_x(const float* __restrict__ x, unsigned short* __restrict__ xb){
  long id = (long)blockIdx.x*256 + threadIdx.x;   // one 8-col chunk
  const int CPR = KP0/8;
  if (id >= (long)N_PAD*CPR) return;
  int row = (int)(id / CPR), c8 = (int)(id % CPR);
  int col = c8*8;
  short8 o;
  if (row < N_NODES && col + 8 <= F_IN) {
    const float* p = &x[(long)row*F_IN + col];
    float4 v0 = *(const float4*)p, v1 = *(const float4*)(p+4);
    o[0]=(short)f2b(v0.x); o[1]=(short)f2b(v0.y); o[2]=(short)f2b(v0.z); o[3]=(short)f2b(v0.w);
    o[4]=(short)f2b(v1.x); o[5]=(short)f2b(v1.y); o[6]=(short)f2b(v1.z); o[7]=(short)f2b(v1.w);
  } else {
    #pragma unroll
    for (int j=0;j<8;j++){
      int cc = col+j;
      float v = (row < N_NODES && cc < F_IN) ? x[(long)row*F_IN + cc] : 0.f;
      o[j] = (short)f2b(v);
    }
  }
  *(short8*)&xb[id*8] = o;
}
__global__ void k_red(const float* __restrict__ p0, const float* __restrict__ p1,
                      unsigned short* __restrict__ tb){
  long i = ((long)blockIdx.x*256 + threadIdx.x)*4;
  if (i >= SZL) return;
  float4 a = *(const float4*)&p0[i];
  float4 b = *(const float4*)&p1[i];
  unsigned short o[4] = { f2b(a.x+b.x), f2b(a.y+b.y), f2b(a.z+b.z), f2b(a.w+b.w) };
  *(uint2*)&tb[i] = *(uint2*)o;
}

// ---------------- bf16 MFMA GEMM: 2-phase double-buffered + k-slot swizzle ----------------
// C[M,N] = A[M,K]@BT[N,K]^T. A,BT bf16 row-major; A must have >= gridDim.y*128 readable rows.
// 128x128 tile, BK=32, 4 waves (2x2), 4x4 16x16x32 frags/wave. gridDim.z = split-K slices.
// LDS layout is k-slot-swizzled: stored[row][p] = global[row][p ^ ((row>>1)&3)] (16B slots).
// GLDS dest stays linear (HW requirement); the swizzle is applied on the global SOURCE
// address and identically on the ds_read address (rule: both-sides-or-neither).
template<int OUTB, int RELU>
__global__ __launch_bounds__(256) void k_gb(
    const unsigned short* __restrict__ A, const unsigned short* __restrict__ BT,
    const float* __restrict__ bias, void* __restrict__ Cvoid,
    int M, int N, int KP, int lda, int ldc, int kchunk, long zstride)
{
  __shared__ unsigned short As[2][128*32];
  __shared__ unsigned short Bs[2][128*32];
  const int tid  = threadIdx.x;
  const int bn   = blockIdx.x * 128;
  const int bm   = blockIdx.y * 128;
  const int z    = blockIdx.z;
  const int wave = tid >> 6, lane = tid & 63;
  const int wm = (wave & 1) * 64, wn = (wave >> 1) * 64;
  const int l15 = lane & 15, l4 = lane >> 4;
  const int k0beg = z * kchunk;
  const int kend0 = k0beg + kchunk;
  const int k0end = (kend0 < KP) ? kend0 : KP;

  f32x4 acc[4][4];
  #pragma unroll
  for (int m=0;m<4;m++)
    #pragma unroll
    for (int n=0;n<4;n++) acc[m][n] = (f32x4){0.f,0.f,0.f,0.f};

  // 16B chunks: tile = 512 chunks = 128 rows x 4 slots; chunk c -> row c>>2, slot c&3.
  // swizzled source slot = (c&3) ^ ((c>>3)&3)
  const int c0 = wave*64 + lane;
  const int c1 = c0 + 256;
  const long ar0 = bm + (c0 >> 2); const int as0 = ((c0 & 3) ^ ((c0 >> 3) & 3))*8;
  const long ar1 = bm + (c1 >> 2); const int as1 = ((c1 & 3) ^ ((c1 >> 3) & 3))*8;
  const long br0 = bn + (c0 >> 2);
  const long br1 = bn + (c1 >> 2);
  const int ldA0 = wave*512;          // ushort offset of this wave's chunk group (issue 0)
  const int ldA1 = 2048 + wave*512;   // issue 1

  // read-side swizzle: k-slot l4 of row (…+l15) lives at slot l4 ^ ((l15>>1)&3)
  const int kro = (l4 ^ ((l15 >> 1) & 3)) * 8;

  const int nit = (k0end - k0beg) >> 5;

  // prologue: stage tile 0 into buffer 0
  {
    const int k0 = k0beg;
    GLDS(A + ar0*lda + (k0 + as0), &As[0][ldA0]);
    GLDS(A + ar1*lda + (k0 + as1), &As[0][ldA1]);
    GLDS(BT + br0*KP + (k0 + as0), &Bs[0][ldA0]);
    GLDS(BT + br1*KP + (k0 + as1), &Bs[0][ldA1]);
  }
  __syncthreads();

  int cur = 0;
  for (int it = 0; it < nit; ++it) {
    // prefetch next tile into the other buffer (overlaps with MFMA below)
    if (it + 1 < nit) {
      const int kn = k0beg + (it+1)*32;
      GLDS(A + ar0*lda + (kn + as0), &As[cur^1][ldA0]);
      GLDS(A + ar1*lda + (kn + as1), &As[cur^1][ldA1]);
      GLDS(BT + br0*KP + (kn + as0), &Bs[cur^1][ldA0]);
      GLDS(BT + br1*KP + (kn + as1), &Bs[cur^1][ldA1]);
    }

    short8 af[4], bf[4];
    #pragma unroll
    for (int m=0;m<4;m++) af[m] = *(const short8*)&As[cur][(wm + m*16 + l15)*32 + kro];
    #pragma unroll
    for (int n=0;n<4;n++) bf[n] = *(const short8*)&Bs[cur][(wn + n*16 + l15)*32 + kro];
    #pragma unroll
    for (int m=0;m<4;m++)
      #pragma unroll
      for (int n=0;n<4;n++)
        acc[m][n] = __builtin_amdgcn_mfma_f32_16x16x32_bf16(af[m], bf[n], acc[m][n], 0, 0, 0);

    __syncthreads();   // drains prefetch (vmcnt0) + all waves' ds_reads (lgkmcnt0)
    cur ^= 1;
  }

  // epilogue: row = bm+wm+m*16+l4*4+r, col = bn+wn+n*16+l15
  #pragma unroll
  for (int m=0;m<4;m++){
    #pragma unroll
    for (int n=0;n<4;n++){
      int col = bn + wn + n*16 + l15;
      if (col >= N) continue;
      float bi = bias ? bias[col] : 0.f;
      #pragma unroll
      for (int r=0;r<4;r++){
        int row = bm + wm + m*16 + l4*4 + r;
        if (row >= M) continue;
        float v = acc[m][n][r] + bi;
        if (RELU) v = fmaxf(v, 0.f);
        if (OUTB) ((unsigned short*)Cvoid)[(long)row*ldc + col] = f2b(v);
        else      (((float*)Cvoid) + z*zstride)[(long)row*ldc + col] = v;
      }
    }
  }
}

// ---------------- GCN aggregation (bf16 h, fp32 accumulate) ----------------
__global__ __launch_bounds__(256) void k_agg(const unsigned short* __restrict__ h,
    const int* __restrict__ rowptr, const int* __restrict__ colsrc,
    const float* __restrict__ dinv, const float* __restrict__ bias,
    float* __restrict__ out)
{
  int d = blockIdx.x;
  int t = threadIdx.x;                 // channel pair 2t,2t+1
  const unsigned* h32 = (const unsigned*)h;
  float di = dinv[d];
  int beg = rowptr[d], end = rowptr[d+1];
  float a0 = 0.f, a1 = 0.f;
  for (int e = beg; e < end; e++) {
    int s = colsrc[e];
    float cf = dinv[s]*di;
    unsigned v = h32[(long)s*256 + t];
    a0 += blo(v)*cf;
    a1 += bhi(v)*cf;
  }
  unsigned v = h32[(long)d*256 + t];
  float sc = di*di;
  a0 += blo(v)*sc;
  a1 += bhi(v)*sc;
  float2 o; o.x = a0 + bias[2*t]; o.y = a1 + bias[2*t+1];
  *(float2*)&out[(long)d*F_H + 2*t] = o;
}

// ---------------- GraphNorm: fused sum+sumsq, then normalize ----------------
#define STAT_ROWS 50
__global__ __launch_bounds__(512) void k_stats(const float* __restrict__ x,
    float* __restrict__ msum, float* __restrict__ ssum){
  int c = threadIdx.x;
  int r0 = blockIdx.x*STAT_ROWS;
  float s = 0.f, s2 = 0.f;
  for (int r=r0;r<r0+STAT_ROWS;r++){ float v = x[(long)r*F_H+c]; s += v; s2 += v*v; }
  atomicAdd(&msum[c], s);
  atomicAdd(&ssum[c], s2);
}
// mode 0: l0f=y, l0b=bf16(y), jkb=bf16(y); mode 1: loutb=bf16(y+l0f), jkb=max; mode 2: jkb=max
__global__ __launch_bounds__(512) void k_final(const float* __restrict__ x,
    const float* __restrict__ msum, const float* __restrict__ ssum,
    const float* __restrict__ w, const float* __restrict__ b, const float* __restrict__ a,
    float* __restrict__ l0f, unsigned short* __restrict__ loutb,
    unsigned short* __restrict__ jkb, int mode)
{
  int c = threadIdx.x;
  float mean = msum[c]*(1.f/N_NODES);
  float aa = a[c];
  float var = ssum[c]*(1.f/N_NODES) - mean*mean*aa*(2.f-aa);
  float inv = rsqrtf(var + EPSV);
  float am = aa*mean;
  float wc = w[c], bc = b[c];
  int r0 = blockIdx.x*STAT_ROWS;
  for (int r=r0;r<r0+STAT_ROWS;r++){
    long idx = (long)r*F_H+c;
    float y = fmaxf(wc*(x[idx]-am)*inv+bc, 0.f);
    if (mode == 0) {
      l0f[idx] = y;
      unsigned short q = f2b(y);
      loutb[idx] = q;
      jkb[idx] = q;
    } else if (mode == 1) {
      loutb[idx] = f2b(y + l0f[idx]);
      float cur = __uint_as_float(((unsigned)jkb[idx])<<16);
      jkb[idx] = f2b(fmaxf(cur, y));
    } else {
      float cur = __uint_as_float(((unsigned)jkb[idx])<<16);
      jkb[idx] = f2b(fmaxf(cur, y));
    }
  }
}

extern "C" void kernel_launch(void* const* d_in, const int* in_sizes, int n_in,
                              void* d_out, int out_size, void* d_ws, size_t ws_size,
                              hipStream_t stream) {
  (void)in_sizes; (void)n_in; (void)out_size; (void)ws_size;
  const float* x     = (const float*)d_in[0];
  const int*   ei    = (const int*)d_in[1];
  const int*   srcp  = ei;
  const int*   dstp  = ei + N_EDGES;
  const float* Wc[3]  = {(const float*)d_in[2], (const float*)d_in[4], (const float*)d_in[6]};
  const float* bc_[3] = {(const float*)d_in[3], (const float*)d_in[5], (const float*)d_in[7]};
  const float* lin1W = (const float*)d_in[8];
  const float* lin1b = (const float*)d_in[9];
  const float* lin2W = (const float*)d_in[10];
  const float* lin2b = (const float*)d_in[11];
  const float* gw[3] = {(const float*)d_in[12], (const float*)d_in[15], (const float*)d_in[18]};
  const float* gb[3] = {(const float*)d_in[13], (const float*)d_in[16], (const float*)d_in[19]};
  const float* ga[3] = {(const float*)d_in[14], (const float*)d_in[17], (const float*)d_in[20]};

  float* out = (float*)d_out;   // out_size = 92,880,000 floats

  // ---- d_out scratch layout (explicit, non-overlapping in time) ----
  float* l0 = out;
  unsigned short* xb   = (unsigned short*)(out + SZL);
  unsigned short* l0b  = (unsigned short*)(out + SZL);
  unsigned short* hinb = (unsigned short*)(out + SZL + ACT);
  unsigned short* jkb  = (unsigned short*)(out + SZL + 2*ACT);
  unsigned short* t_b  = (unsigned short*)(out + SZL + 3*ACT);
  float* p1            = out + 57200000L;

  // ---- ws layout (~74.6 MB) ----
  float* ws   = (float*)d_ws;
  float* p0   = ws;                         // conv0 partial z=0; reused as `agg` afterwards
  float* agg  = ws;
  unsigned short* f1b = (unsigned short*)(ws + SZL);            // lin1 out: ACT floats
  long off = SZL + ACT;
  unsigned short* W0T   = (unsigned short*)(ws + off); off += (long)F_H*KP0/2;
  unsigned short* W1T   = (unsigned short*)(ws + off); off += (long)F_H*F_H/2;
  unsigned short* W2T   = (unsigned short*)(ws + off); off += (long)F_H*F_H/2;
  unsigned short* l1WT  = (unsigned short*)(ws + off); off += (long)F_H*F_H/2;
  unsigned short* l2WT  = (unsigned short*)(ws + off); off += (long)NP2*F_H/2;
  float* dinv = ws + off;                   off += N_NODES;
  float* msum = ws + off;                   off += F_H;
  float* ssum = ws + off;                   off += F_H;
  int* deg    = (int*)(ws + off);           off += N_NODES;
  int* rowptr = (int*)(ws + off);           off += N_NODES + 1;
  int* cursor = (int*)(ws + off);           off += N_NODES;
  int* colsrc = (int*)(ws + off);

  // ---- CSR build ----
  k_zero_i<<<(N_NODES+255)/256,256,0,stream>>>(deg, N_NODES);
  k_degree<<<(N_EDGES+255)/256,256,0,stream>>>(dstp, deg);
  k_dinv<<<(N_NODES+255)/256,256,0,stream>>>(deg, dinv);
  k_scan<<<1,1024,0,stream>>>(deg, rowptr);
  k_copy_i<<<(N_NODES+255)/256,256,0,stream>>>(rowptr, cursor, N_NODES);
  k_scatter<<<(N_EDGES+255)/256,256,0,stream>>>(srcp, dstp, cursor, colsrc);

  // ---- conversions ----
  {
    long nx = (long)N_PAD*(KP0/8);
    k_cvt_x<<<(int)((nx+255)/256),256,0,stream>>>(x, xb);
    int n0 = F_H*KP0;   k_cvtT<<<(n0+255)/256,256,0,stream>>>(Wc[0], W0T, F_IN, F_H, F_H, KP0);
    int nh = F_H*F_H;   k_cvtT<<<(nh+255)/256,256,0,stream>>>(Wc[1], W1T, F_H, F_H, F_H, F_H);
                        k_cvtT<<<(nh+255)/256,256,0,stream>>>(Wc[2], W2T, F_H, F_H, F_H, F_H);
                        k_cvtT<<<(nh+255)/256,256,0,stream>>>(lin1W, l1WT, F_H, F_H, F_H, F_H);
    int n2 = NP2*F_H;   k_cvtT<<<(n2+255)/256,256,0,stream>>>(lin2W, l2WT, F_H, F_IN, NP2, F_H);
  }

  // ---- 3 GCN layers ----
  for (int i = 0; i < 3; i++) {
    if (i == 0) {
      // split-K=2: z=0 -> p0 (ws), z=1 -> p1 (d_out); zstride maps p0+zstride == p1
      long zs = p1 - p0;
      k_gb<0,0><<<dim3(F_H/128, N_PAD/128, 2),256,0,stream>>>(xb, W0T, nullptr, p0,
          N_NODES, F_H, KP0, KP0, F_H, KP0/2, zs);
      k_red<<<(int)((SZL/4+255)/256),256,0,stream>>>(p0, p1, t_b);   // xb dead by now
    } else {
      const unsigned short* Ain = (i==1) ? l0b : hinb;
      const unsigned short* Wt  = (i==1) ? W1T : W2T;
      k_gb<1,0><<<dim3(F_H/128, N_PAD/128, 1),256,0,stream>>>(Ain, Wt, nullptr, t_b,
          N_NODES, F_H, F_H, F_H, F_H, F_H, 0L);
    }
    k_agg<<<N_NODES,256,0,stream>>>(t_b, rowptr, colsrc, dinv, bc_[i], agg);
    k_zero_f<<<4,256,0,stream>>>(msum, 1024);   // msum+ssum contiguous
    k_stats<<<N_NODES/STAT_ROWS,512,0,stream>>>(agg, msum, ssum);
    k_final<<<N_NODES/STAT_ROWS,512,0,stream>>>(agg, msum, ssum, gw[i], gb[i], ga[i],
        l0, (i==0)? l0b : hinb, jkb, i);
  }

  // ---- head ----
  k_gb<1,1><<<dim3(F_H/128, N_PAD/128, 1),256,0,stream>>>(jkb, l1WT, lin1b, f1b,
      N_NODES, F_H, F_H, F_H, F_H, F_H, 0L);
  k_gb<0,0><<<dim3(NP2/128, N_PAD/128, 1),256,0,stream>>>(f1b, l2WT, lin2b, out,
      N_NODES, F_IN, F_H, F_H, F_IN, F_H, 0L);
}

// Round 6
// 1059.719 us; speedup vs baseline: 3.5447x; 1.0360x over previous
//
#include <hip/hip_runtime.h>

#define N_NODES 20000
#define N_PAD   20096      /* 157*128 */
#define N_EDGES 320000
#define F_IN 4644
#define KP0  4672          /* F_IN padded to 32 */
#define NP2  4736          /* F_IN padded to 128 */
#define F_H 512
#define EPSV 1e-5f
#define SZL 10240000L      /* N_NODES*F_H floats */
#define ACT 5200000L       /* floats per bf16 activation buffer: >= N_PAD*F_H/2 = 5,144,576 */

using short8 = __attribute__((ext_vector_type(8))) short;
using f32x4  = __attribute__((ext_vector_type(4))) float;

__device__ inline unsigned short f2b(float f){
  union{float f; unsigned u;} v; v.f=f;
  unsigned u = v.u + 0x7fffu + ((v.u>>16)&1u);
  return (unsigned short)(u>>16);
}
__device__ inline float blo(unsigned v){ return __uint_as_float(v<<16); }
__device__ inline float bhi(unsigned v){ return __uint_as_float(v & 0xffff0000u); }

#define GLDS(g, l) __builtin_amdgcn_global_load_lds( \
    (const __attribute__((address_space(1))) void*)(g), \
    (__attribute__((address_space(3))) void*)(l), 16, 0, 0)

// ---------------- utility / CSR ----------------
__global__ void k_zero_i(int* p, int n){ int i = blockIdx.x*blockDim.x+threadIdx.x; if(i<n) p[i]=0; }
__global__ void k_zero_f(float* p, int n){ int i = blockIdx.x*blockDim.x+threadIdx.x; if(i<n) p[i]=0.f; }

__global__ void k_degree(const int* __restrict__ dst, int* __restrict__ deg){
  int e = blockIdx.x*blockDim.x+threadIdx.x;
  if (e < N_EDGES) atomicAdd(&deg[dst[e]], 1);
}
__global__ void k_dinv(const int* __restrict__ deg, float* __restrict__ dinv){
  int i = blockIdx.x*blockDim.x+threadIdx.x;
  if (i < N_NODES) dinv[i] = rsqrtf((float)(deg[i]+1));
}
__global__ __launch_bounds__(1024) void k_scan(const int* __restrict__ deg, int* __restrict__ rowptr){
  __shared__ int sh[1024];
  int t = threadIdx.x;
  const int C = 20;
  int base = t*C;
  int loc[C];
  int s = 0;
  #pragma unroll
  for (int i=0;i<C;i++){ int idx=base+i; int v = (idx<N_NODES)?deg[idx]:0; loc[i]=s; s+=v; }
  sh[t]=s; __syncthreads();
  for (int off=1; off<1024; off<<=1){
    int v = (t>=off)?sh[t-off]:0;
    __syncthreads();
    sh[t]+=v;
    __syncthreads();
  }
  int excl = (t==0)?0:sh[t-1];
  #pragma unroll
  for (int i=0;i<C;i++){ int idx=base+i; if(idx<N_NODES) rowptr[idx]=excl+loc[i]; }
  if (t==1023) rowptr[N_NODES]=sh[1023];
}
__global__ void k_copy_i(const int* __restrict__ a, int* __restrict__ b, int n){
  int i = blockIdx.x*blockDim.x+threadIdx.x; if(i<n) b[i]=a[i];
}
__global__ void k_scatter(const int* __restrict__ src, const int* __restrict__ dst,
                          int* __restrict__ cursor, int* __restrict__ colsrc){
  int e = blockIdx.x*blockDim.x+threadIdx.x;
  if (e < N_EDGES){
    int p = atomicAdd(&cursor[dst[e]], 1);
    colsrc[p] = src[e];
  }
}

// ---------------- conversions ----------------
__global__ void k_cvtT(const float* __restrict__ B, unsigned short* __restrict__ BT,
                       int K, int N, int NP, int KP){
  int t = blockIdx.x*blockDim.x+threadIdx.x;
  if (t >= NP*KP) return;
  int n = t / KP, k = t % KP;
  float v = (n < N && k < K) ? B[(long)k*N + n] : 0.f;
  BT[t] = f2b(v);
}
__global__ void k_cvt_x(const float* __restrict__ x, unsigned short* __restrict__ xb){
  long id = (long)blockIdx.x*256 + threadIdx.x;   // one 8-col chunk
  const int CPR = KP0/8;
  if (id >= (long)N_PAD*CPR) return;
  int row = (int)(id / CPR), c8 = (int)(id % CPR);
  int col = c8*8;
  short8 o;
  if (row < N_NODES && col + 8 <= F_IN) {
    const float* p = &x[(long)row*F_IN + col];
    float4 v0 = *(const float4*)p, v1 = *(const float4*)(p+4);
    o[0]=(short)f2b(v0.x); o[1]=(short)f2b(v0.y); o[2]=(short)f2b(v0.z); o[3]=(short)f2b(v0.w);
    o[4]=(short)f2b(v1.x); o[5]=(short)f2b(v1.y); o[6]=(short)f2b(v1.z); o[7]=(short)f2b(v1.w);
  } else {
    #pragma unroll
    for (int j=0;j<8;j++){
      int cc = col+j;
      float v = (row < N_NODES && cc < F_IN) ? x[(long)row*F_IN + cc] : 0.f;
      o[j] = (short)f2b(v);
    }
  }
  *(short8*)&xb[id*8] = o;
}
__global__ void k_red(const float* __restrict__ p0, const float* __restrict__ p1,
                      unsigned short* __restrict__ tb){
  long i = ((long)blockIdx.x*256 + threadIdx.x)*4;
  if (i >= SZL) return;
  float4 a = *(const float4*)&p0[i];
  float4 b = *(const float4*)&p1[i];
  unsigned short o[4] = { f2b(a.x+b.x), f2b(a.y+b.y), f2b(a.z+b.z), f2b(a.w+b.w) };
  *(uint2*)&tb[i] = *(uint2*)o;
}

// ---------------- bf16 MFMA GEMM: dbuf + k-slot swizzle + full-line epilogue ----------------
// C[M,N] = A[M,K]@BT[N,K]^T. A,BT bf16 row-major; A must have >= gridDim.y*128 readable rows.
// 128x128 tile, BK=32, 4 waves (2x2), 4x4 16x16x32 frags/wave. gridDim.z = split-K slices.
// LDS k-slot swizzle: stored[row][p] = global[row][p ^ ((row>>1)&3)] (16B slots); GLDS dest
// linear, swizzle on global source + ds_read address (both-sides rule).
// Epilogue: per-wave LDS transpose -> float4 (or 4xushort) stores, 256B/128B contiguous per
// instruction => full cache lines, no write-allocate RMW fetches.
template<int OUTB, int RELU>
__global__ __launch_bounds__(256) void k_gb(
    const unsigned short* __restrict__ A, const unsigned short* __restrict__ BT,
    const float* __restrict__ bias, void* __restrict__ Cvoid,
    int M, int N, int KP, int lda, int ldc, int kchunk, long zstride)
{
  // [0..1] = A double-buffer, [2..3] = B double-buffer; epilogue reuses as fp32 scratch
  __shared__ unsigned short smem[4][4096];
  const int tid  = threadIdx.x;
  const int bn   = blockIdx.x * 128;
  const int bm   = blockIdx.y * 128;
  const int z    = blockIdx.z;
  const int wave = tid >> 6, lane = tid & 63;
  const int wm = (wave & 1) * 64, wn = (wave >> 1) * 64;
  const int l15 = lane & 15, l4 = lane >> 4;
  const int k0beg = z * kchunk;
  const int kend0 = k0beg + kchunk;
  const int k0end = (kend0 < KP) ? kend0 : KP;

  f32x4 acc[4][4];
  #pragma unroll
  for (int m=0;m<4;m++)
    #pragma unroll
    for (int n=0;n<4;n++) acc[m][n] = (f32x4){0.f,0.f,0.f,0.f};

  // 16B chunks: tile = 512 chunks = 128 rows x 4 slots; chunk c -> row c>>2, slot c&3.
  const int c0 = wave*64 + lane;
  const int c1 = c0 + 256;
  const long ar0 = bm + (c0 >> 2); const int as0 = ((c0 & 3) ^ ((c0 >> 3) & 3))*8;
  const long ar1 = bm + (c1 >> 2); const int as1 = ((c1 & 3) ^ ((c1 >> 3) & 3))*8;
  const long br0 = bn + (c0 >> 2);
  const long br1 = bn + (c1 >> 2);
  const int ldA0 = wave*512;          // ushort offset of this wave's chunk group (issue 0)
  const int ldA1 = 2048 + wave*512;   // issue 1

  // read-side swizzle: k-slot l4 of row (…+l15) lives at slot l4 ^ ((l15>>1)&3)
  const int kro = (l4 ^ ((l15 >> 1) & 3)) * 8;

  const int nit = (k0end - k0beg) >> 5;

  // prologue: stage tile 0 into buffer 0
  {
    const int k0 = k0beg;
    GLDS(A + ar0*lda + (k0 + as0), &smem[0][ldA0]);
    GLDS(A + ar1*lda + (k0 + as1), &smem[0][ldA1]);
    GLDS(BT + br0*KP + (k0 + as0), &smem[2][ldA0]);
    GLDS(BT + br1*KP + (k0 + as1), &smem[2][ldA1]);
  }
  __syncthreads();

  int cur = 0;
  for (int it = 0; it < nit; ++it) {
    if (it + 1 < nit) {
      const int kn = k0beg + (it+1)*32;
      GLDS(A + ar0*lda + (kn + as0), &smem[cur^1][ldA0]);
      GLDS(A + ar1*lda + (kn + as1), &smem[cur^1][ldA1]);
      GLDS(BT + br0*KP + (kn + as0), &smem[2+(cur^1)][ldA0]);
      GLDS(BT + br1*KP + (kn + as1), &smem[2+(cur^1)][ldA1]);
    }

    short8 af[4], bf[4];
    #pragma unroll
    for (int m=0;m<4;m++) af[m] = *(const short8*)&smem[cur][(wm + m*16 + l15)*32 + kro];
    #pragma unroll
    for (int n=0;n<4;n++) bf[n] = *(const short8*)&smem[2+cur][(wn + n*16 + l15)*32 + kro];
    #pragma unroll
    for (int m=0;m<4;m++)
      #pragma unroll
      for (int n=0;n<4;n++)
        acc[m][n] = __builtin_amdgcn_mfma_f32_16x16x32_bf16(af[m], bf[n], acc[m][n], 0, 0, 0);

    __syncthreads();   // drains prefetch + all waves' ds_reads
    cur ^= 1;
  }

  // ---- full-line epilogue via per-wave LDS transpose ----
  // per wave: 16 rows x 64 cols fp32, row stride 68 (16B-aligned, conflict-light)
  float* eb = ((float*)smem) + wave*1088;   // 4*1088*4B = 17408B <= 32KB
  float* Cf = ((float*)Cvoid) + z*zstride;
  unsigned short* Cb = (unsigned short*)Cvoid;
  #pragma unroll
  for (int m=0;m<4;m++){
    #pragma unroll
    for (int n=0;n<4;n++)
      #pragma unroll
      for (int r=0;r<4;r++)
        eb[(l4*4+r)*68 + n*16 + l15] = acc[m][n][r];
    __syncthreads();
    const int row0 = bm + wm + m*16;
    #pragma unroll
    for (int i=0;i<4;i++){
      int idx = i*64 + lane;          // 0..255 float4-chunks of the 16x64 tile
      int rr  = idx >> 4;             // 0..15
      int c4  = (idx & 15) * 4;       // 0,4,..,60
      int row = row0 + rr;
      int col = bn + wn + c4;
      if (row < M) {
        float4 v = *(float4*)&eb[rr*68 + c4];
        float vv[4] = {v.x, v.y, v.z, v.w};
        if (col + 3 < N) {
          #pragma unroll
          for (int j=0;j<4;j++){
            float zz = vv[j] + (bias ? bias[col+j] : 0.f);
            vv[j] = RELU ? fmaxf(zz, 0.f) : zz;
          }
          if (OUTB) {
            unsigned short o[4] = { f2b(vv[0]), f2b(vv[1]), f2b(vv[2]), f2b(vv[3]) };
            *(uint2*)&Cb[(long)row*ldc + col] = *(uint2*)o;
          } else {
            float4 ov = {vv[0], vv[1], vv[2], vv[3]};
            *(float4*)&Cf[(long)row*ldc + col] = ov;
          }
        } else {
          #pragma unroll
          for (int j=0;j<4;j++){
            int cc = col + j;
            if (cc < N) {
              float zz = vv[j] + (bias ? bias[cc] : 0.f);
              if (RELU) zz = fmaxf(zz, 0.f);
              if (OUTB) Cb[(long)row*ldc + cc] = f2b(zz);
              else      Cf[(long)row*ldc + cc] = zz;
            }
          }
        }
      }
    }
    __syncthreads();
  }
}

// ---------------- GCN aggregation (bf16 h, fp32 accumulate) ----------------
__global__ __launch_bounds__(256) void k_agg(const unsigned short* __restrict__ h,
    const int* __restrict__ rowptr, const int* __restrict__ colsrc,
    const float* __restrict__ dinv, const float* __restrict__ bias,
    float* __restrict__ out)
{
  int d = blockIdx.x;
  int t = threadIdx.x;                 // channel pair 2t,2t+1
  const unsigned* h32 = (const unsigned*)h;
  float di = dinv[d];
  int beg = rowptr[d], end = rowptr[d+1];
  float a0 = 0.f, a1 = 0.f;
  for (int e = beg; e < end; e++) {
    int s = colsrc[e];
    float cf = dinv[s]*di;
    unsigned v = h32[(long)s*256 + t];
    a0 += blo(v)*cf;
    a1 += bhi(v)*cf;
  }
  unsigned v = h32[(long)d*256 + t];
  float sc = di*di;
  a0 += blo(v)*sc;
  a1 += bhi(v)*sc;
  float2 o; o.x = a0 + bias[2*t]; o.y = a1 + bias[2*t+1];
  *(float2*)&out[(long)d*F_H + 2*t] = o;
}

// ---------------- GraphNorm: fused sum+sumsq, then normalize ----------------
#define STAT_ROWS 50
__global__ __launch_bounds__(512) void k_stats(const float* __restrict__ x,
    float* __restrict__ msum, float* __restrict__ ssum){
  int c = threadIdx.x;
  int r0 = blockIdx.x*STAT_ROWS;
  float s = 0.f, s2 = 0.f;
  for (int r=r0;r<r0+STAT_ROWS;r++){ float v = x[(long)r*F_H+c]; s += v; s2 += v*v; }
  atomicAdd(&msum[c], s);
  atomicAdd(&ssum[c], s2);
}
// mode 0: l0f=y, l0b=bf16(y), jkb=bf16(y); mode 1: loutb=bf16(y+l0f), jkb=max; mode 2: jkb=max
__global__ __launch_bounds__(512) void k_final(const float* __restrict__ x,
    const float* __restrict__ msum, const float* __restrict__ ssum,
    const float* __restrict__ w, const float* __restrict__ b, const float* __restrict__ a,
    float* __restrict__ l0f, unsigned short* __restrict__ loutb,
    unsigned short* __restrict__ jkb, int mode)
{
  int c = threadIdx.x;
  float mean = msum[c]*(1.f/N_NODES);
  float aa = a[c];
  float var = ssum[c]*(1.f/N_NODES) - mean*mean*aa*(2.f-aa);
  float inv = rsqrtf(var + EPSV);
  float am = aa*mean;
  float wc = w[c], bc = b[c];
  int r0 = blockIdx.x*STAT_ROWS;
  for (int r=r0;r<r0+STAT_ROWS;r++){
    long idx = (long)r*F_H+c;
    float y = fmaxf(wc*(x[idx]-am)*inv+bc, 0.f);
    if (mode == 0) {
      l0f[idx] = y;
      unsigned short q = f2b(y);
      loutb[idx] = q;
      jkb[idx] = q;
    } else if (mode == 1) {
      loutb[idx] = f2b(y + l0f[idx]);
      float cur = __uint_as_float(((unsigned)jkb[idx])<<16);
      jkb[idx] = f2b(fmaxf(cur, y));
    } else {
      float cur = __uint_as_float(((unsigned)jkb[idx])<<16);
      jkb[idx] = f2b(fmaxf(cur, y));
    }
  }
}

extern "C" void kernel_launch(void* const* d_in, const int* in_sizes, int n_in,
                              void* d_out, int out_size, void* d_ws, size_t ws_size,
                              hipStream_t stream) {
  (void)in_sizes; (void)n_in; (void)out_size; (void)ws_size;
  const float* x     = (const float*)d_in[0];
  const int*   ei    = (const int*)d_in[1];
  const int*   srcp  = ei;
  const int*   dstp  = ei + N_EDGES;
  const float* Wc[3]  = {(const float*)d_in[2], (const float*)d_in[4], (const float*)d_in[6]};
  const float* bc_[3] = {(const float*)d_in[3], (const float*)d_in[5], (const float*)d_in[7]};
  const float* lin1W = (const float*)d_in[8];
  const float* lin1b = (const float*)d_in[9];
  const float* lin2W = (const float*)d_in[10];
  const float* lin2b = (const float*)d_in[11];
  const float* gw[3] = {(const float*)d_in[12], (const float*)d_in[15], (const float*)d_in[18]};
  const float* gb[3] = {(const float*)d_in[13], (const float*)d_in[16], (const float*)d_in[19]};
  const float* ga[3] = {(const float*)d_in[14], (const float*)d_in[17], (const float*)d_in[20]};

  float* out = (float*)d_out;   // out_size = 92,880,000 floats

  // ---- d_out scratch layout (explicit, non-overlapping in time) ----
  float* l0 = out;
  unsigned short* xb   = (unsigned short*)(out + SZL);
  unsigned short* l0b  = (unsigned short*)(out + SZL);
  unsigned short* hinb = (unsigned short*)(out + SZL + ACT);
  unsigned short* jkb  = (unsigned short*)(out + SZL + 2*ACT);
  unsigned short* t_b  = (unsigned short*)(out + SZL + 3*ACT);
  float* p1            = out + 57200000L;

  // ---- ws layout (~74.6 MB) ----
  float* ws   = (float*)d_ws;
  float* p0   = ws;                         // conv0 partial z=0; reused as `agg` afterwards
  float* agg  = ws;
  unsigned short* f1b = (unsigned short*)(ws + SZL);            // lin1 out: ACT floats
  long off = SZL + ACT;
  unsigned short* W0T   = (unsigned short*)(ws + off); off += (long)F_H*KP0/2;
  unsigned short* W1T   = (unsigned short*)(ws + off); off += (long)F_H*F_H/2;
  unsigned short* W2T   = (unsigned short*)(ws + off); off += (long)F_H*F_H/2;
  unsigned short* l1WT  = (unsigned short*)(ws + off); off += (long)F_H*F_H/2;
  unsigned short* l2WT  = (unsigned short*)(ws + off); off += (long)NP2*F_H/2;
  float* dinv = ws + off;                   off += N_NODES;
  float* msum = ws + off;                   off += F_H;
  float* ssum = ws + off;                   off += F_H;
  int* deg    = (int*)(ws + off);           off += N_NODES;
  int* rowptr = (int*)(ws + off);           off += N_NODES + 1;
  int* cursor = (int*)(ws + off);           off += N_NODES;
  int* colsrc = (int*)(ws + off);

  // ---- CSR build ----
  k_zero_i<<<(N_NODES+255)/256,256,0,stream>>>(deg, N_NODES);
  k_degree<<<(N_EDGES+255)/256,256,0,stream>>>(dstp, deg);
  k_dinv<<<(N_NODES+255)/256,256,0,stream>>>(deg, dinv);
  k_scan<<<1,1024,0,stream>>>(deg, rowptr);
  k_copy_i<<<(N_NODES+255)/256,256,0,stream>>>(rowptr, cursor, N_NODES);
  k_scatter<<<(N_EDGES+255)/256,256,0,stream>>>(srcp, dstp, cursor, colsrc);

  // ---- conversions ----
  {
    long nx = (long)N_PAD*(KP0/8);
    k_cvt_x<<<(int)((nx+255)/256),256,0,stream>>>(x, xb);
    int n0 = F_H*KP0;   k_cvtT<<<(n0+255)/256,256,0,stream>>>(Wc[0], W0T, F_IN, F_H, F_H, KP0);
    int nh = F_H*F_H;   k_cvtT<<<(nh+255)/256,256,0,stream>>>(Wc[1], W1T, F_H, F_H, F_H, F_H);
                        k_cvtT<<<(nh+255)/256,256,0,stream>>>(Wc[2], W2T, F_H, F_H, F_H, F_H);
                        k_cvtT<<<(nh+255)/256,256,0,stream>>>(lin1W, l1WT, F_H, F_H, F_H, F_H);
    int n2 = NP2*F_H;   k_cvtT<<<(n2+255)/256,256,0,stream>>>(lin2W, l2WT, F_H, F_IN, NP2, F_H);
  }

  // ---- 3 GCN layers ----
  for (int i = 0; i < 3; i++) {
    if (i == 0) {
      // split-K=2: z=0 -> p0 (ws), z=1 -> p1 (d_out); zstride maps p0+zstride == p1
      long zs = p1 - p0;
      k_gb<0,0><<<dim3(F_H/128, N_PAD/128, 2),256,0,stream>>>(xb, W0T, nullptr, p0,
          N_NODES, F_H, KP0, KP0, F_H, KP0/2, zs);
      k_red<<<(int)((SZL/4+255)/256),256,0,stream>>>(p0, p1, t_b);   // xb dead by now
    } else {
      const unsigned short* Ain = (i==1) ? l0b : hinb;
      const unsigned short* Wt  = (i==1) ? W1T : W2T;
      k_gb<1,0><<<dim3(F_H/128, N_PAD/128, 1),256,0,stream>>>(Ain, Wt, nullptr, t_b,
          N_NODES, F_H, F_H, F_H, F_H, F_H, 0L);
    }
    k_agg<<<N_NODES,256,0,stream>>>(t_b, rowptr, colsrc, dinv, bc_[i], agg);
    k_zero_f<<<4,256,0,stream>>>(msum, 1024);   // msum+ssum contiguous
    k_stats<<<N_NODES/STAT_ROWS,512,0,stream>>>(agg, msum, ssum);
    k_final<<<N_NODES/STAT_ROWS,512,0,stream>>>(agg, msum, ssum, gw[i], gb[i], ga[i],
        l0, (i==0)? l0b : hinb, jkb, i);
  }

  // ---- head ----
  k_gb<1,1><<<dim3(F_H/128, N_PAD/128, 1),256,0,stream>>>(jkb, l1WT, lin1b, f1b,
      N_NODES, F_H, F_H, F_H, F_H, F_H, 0L);
  k_gb<0,0><<<dim3(NP2/128, N_PAD/128, 1),256,0,stream>>>(f1b, l2WT, lin2b, out,
      N_NODES, F_IN, F_H, F_H, F_IN, F_H, 0L);
}

// Round 7
// 1025.151 us; speedup vs baseline: 3.6642x; 1.0337x over previous
//
#include <hip/hip_runtime.h>

#define N_NODES 20000
#define N_PAD   20096      /* 157*128 */
#define N_EDGES 320000
#define F_IN 4644
#define KP0  4672          /* F_IN padded to 32 */
#define NP2  4736          /* F_IN padded to 128 */
#define F_H 512
#define EPSV 1e-5f
#define SZL 10240000L      /* N_NODES*F_H floats */
#define ACT 5200000L       /* floats per bf16 activation buffer: >= N_PAD*F_H/2 = 5,144,576 */

using short8 = __attribute__((ext_vector_type(8))) short;
using f32x4  = __attribute__((ext_vector_type(4))) float;

__device__ inline unsigned short f2b(float f){
  union{float f; unsigned u;} v; v.f=f;
  unsigned u = v.u + 0x7fffu + ((v.u>>16)&1u);
  return (unsigned short)(u>>16);
}
__device__ inline float blo(unsigned v){ return __uint_as_float(v<<16); }
__device__ inline float bhi(unsigned v){ return __uint_as_float(v & 0xffff0000u); }

#define GLDS(g, l) __builtin_amdgcn_global_load_lds( \
    (const __attribute__((address_space(1))) void*)(g), \
    (__attribute__((address_space(3))) void*)(l), 16, 0, 0)

// ---------------- utility / CSR ----------------
__global__ void k_zero_i(int* p, int n){ int i = blockIdx.x*blockDim.x+threadIdx.x; if(i<n) p[i]=0; }
__global__ void k_zero_f(float* p, int n){ int i = blockIdx.x*blockDim.x+threadIdx.x; if(i<n) p[i]=0.f; }

__global__ void k_degree(const int* __restrict__ dst, int* __restrict__ deg){
  int e = blockIdx.x*blockDim.x+threadIdx.x;
  if (e < N_EDGES) atomicAdd(&deg[dst[e]], 1);
}
__global__ void k_dinv(const int* __restrict__ deg, float* __restrict__ dinv){
  int i = blockIdx.x*blockDim.x+threadIdx.x;
  if (i < N_NODES) dinv[i] = rsqrtf((float)(deg[i]+1));
}
__global__ __launch_bounds__(1024) void k_scan(const int* __restrict__ deg, int* __restrict__ rowptr){
  __shared__ int sh[1024];
  int t = threadIdx.x;
  const int C = 20;
  int base = t*C;
  int loc[C];
  int s = 0;
  #pragma unroll
  for (int i=0;i<C;i++){ int idx=base+i; int v = (idx<N_NODES)?deg[idx]:0; loc[i]=s; s+=v; }
  sh[t]=s; __syncthreads();
  for (int off=1; off<1024; off<<=1){
    int v = (t>=off)?sh[t-off]:0;
    __syncthreads();
    sh[t]+=v;
    __syncthreads();
  }
  int excl = (t==0)?0:sh[t-1];
  #pragma unroll
  for (int i=0;i<C;i++){ int idx=base+i; if(idx<N_NODES) rowptr[idx]=excl+loc[i]; }
  if (t==1023) rowptr[N_NODES]=sh[1023];
}
__global__ void k_copy_i(const int* __restrict__ a, int* __restrict__ b, int n){
  int i = blockIdx.x*blockDim.x+threadIdx.x; if(i<n) b[i]=a[i];
}
__global__ void k_scatter(const int* __restrict__ src, const int* __restrict__ dst,
                          int* __restrict__ cursor, int* __restrict__ colsrc){
  int e = blockIdx.x*blockDim.x+threadIdx.x;
  if (e < N_EDGES){
    int p = atomicAdd(&cursor[dst[e]], 1);
    colsrc[p] = src[e];
  }
}

// ---------------- conversions ----------------
__global__ void k_cvtT(const float* __restrict__ B, unsigned short* __restrict__ BT,
                       int K, int N, int NP, int KP){
  int t = blockIdx.x*blockDim.x+threadIdx.x;
  if (t >= NP*KP) return;
  int n = t / KP, k = t % KP;
  float v = (n < N && k < K) ? B[(long)k*N + n] : 0.f;
  BT[t] = f2b(v);
}
__global__ void k_cvt_x(const float* __restrict__ x, unsigned short* __restrict__ xb){
  long id = (long)blockIdx.x*256 + threadIdx.x;   // one 8-col chunk
  const int CPR = KP0/8;
  if (id >= (long)N_PAD*CPR) return;
  int row = (int)(id / CPR), c8 = (int)(id % CPR);
  int col = c8*8;
  short8 o;
  if (row < N_NODES && col + 8 <= F_IN) {
    const float* p = &x[(long)row*F_IN + col];
    float4 v0 = *(const float4*)p, v1 = *(const float4*)(p+4);
    o[0]=(short)f2b(v0.x); o[1]=(short)f2b(v0.y); o[2]=(short)f2b(v0.z); o[3]=(short)f2b(v0.w);
    o[4]=(short)f2b(v1.x); o[5]=(short)f2b(v1.y); o[6]=(short)f2b(v1.z); o[7]=(short)f2b(v1.w);
  } else {
    #pragma unroll
    for (int j=0;j<8;j++){
      int cc = col+j;
      float v = (row < N_NODES && cc < F_IN) ? x[(long)row*F_IN + cc] : 0.f;
      o[j] = (short)f2b(v);
    }
  }
  *(short8*)&xb[id*8] = o;
}
__global__ void k_red(const float* __restrict__ p0, const float* __restrict__ p1,
                      unsigned short* __restrict__ tb){
  long i = ((long)blockIdx.x*256 + threadIdx.x)*4;
  if (i >= SZL) return;
  float4 a = *(const float4*)&p0[i];
  float4 b = *(const float4*)&p1[i];
  unsigned short o[4] = { f2b(a.x+b.x), f2b(a.y+b.y), f2b(a.z+b.z), f2b(a.w+b.w) };
  *(uint2*)&tb[i] = *(uint2*)o;
}

// ---------------- bf16 MFMA GEMM: dbuf + swizzles + full-line epilogue ----------------
// C[M,N] = A[M,K]@BT[N,K]^T. A,BT bf16 row-major; A must have >= (nwg/gx)*128 readable rows.
// 128x128 tile, BK=32, 4 waves (2x2), 4x4 16x16x32 frags/wave. gridDim.z = split-K slices.
// XCD-aware bijective block swizzle (T1/m204): each XCD gets a contiguous x-major chunk so
// blocks sharing an A-panel land on the same XCD's L2 (A read ~once from HBM).
// LDS k-slot swizzle: stored[row][p] = global[row][p ^ ((row>>1)&3)] (16B slots); GLDS dest
// linear, swizzle on global source + ds_read address (both-sides rule).
// Epilogue: per-wave LDS transpose -> float4 / 4xushort stores (full cache lines).
template<int OUTB, int RELU>
__global__ __launch_bounds__(256) void k_gb(
    const unsigned short* __restrict__ A, const unsigned short* __restrict__ BT,
    const float* __restrict__ bias, void* __restrict__ Cvoid,
    int M, int N, int KP, int lda, int ldc, int kchunk, long zstride)
{
  // [0..1] = A double-buffer, [2..3] = B double-buffer; epilogue reuses as fp32 scratch
  __shared__ unsigned short smem[4][4096];
  const int tid  = threadIdx.x;
  // ---- XCD-aware bijective swizzle over flattened (x,y) ----
  const int gx   = gridDim.x;
  const int nwg  = gx * gridDim.y;
  const int orig = blockIdx.x + gx * blockIdx.y;
  const int q = nwg >> 3, r = nwg & 7;
  const int xcd = orig & 7, sub = orig >> 3;
  const int wg  = (xcd < r ? xcd*(q+1) : r*(q+1) + (xcd - r)*q) + sub;
  const int bn  = (wg % gx) * 128;
  const int bm  = (wg / gx) * 128;
  const int z    = blockIdx.z;
  const int wave = tid >> 6, lane = tid & 63;
  const int wm = (wave & 1) * 64, wn = (wave >> 1) * 64;
  const int l15 = lane & 15, l4 = lane >> 4;
  const int k0beg = z * kchunk;
  const int kend0 = k0beg + kchunk;
  const int k0end = (kend0 < KP) ? kend0 : KP;

  f32x4 acc[4][4];
  #pragma unroll
  for (int m=0;m<4;m++)
    #pragma unroll
    for (int n=0;n<4;n++) acc[m][n] = (f32x4){0.f,0.f,0.f,0.f};

  // 16B chunks: tile = 512 chunks = 128 rows x 4 slots; chunk c -> row c>>2, slot c&3.
  const int c0 = wave*64 + lane;
  const int c1 = c0 + 256;
  const long ar0 = bm + (c0 >> 2); const int as0 = ((c0 & 3) ^ ((c0 >> 3) & 3))*8;
  const long ar1 = bm + (c1 >> 2); const int as1 = ((c1 & 3) ^ ((c1 >> 3) & 3))*8;
  const long br0 = bn + (c0 >> 2);
  const long br1 = bn + (c1 >> 2);
  const int ldA0 = wave*512;          // ushort offset of this wave's chunk group (issue 0)
  const int ldA1 = 2048 + wave*512;   // issue 1

  // read-side swizzle: k-slot l4 of row (…+l15) lives at slot l4 ^ ((l15>>1)&3)
  const int kro = (l4 ^ ((l15 >> 1) & 3)) * 8;

  const int nit = (k0end - k0beg) >> 5;

  // prologue: stage tile 0 into buffer 0
  {
    const int k0 = k0beg;
    GLDS(A + ar0*lda + (k0 + as0), &smem[0][ldA0]);
    GLDS(A + ar1*lda + (k0 + as1), &smem[0][ldA1]);
    GLDS(BT + br0*KP + (k0 + as0), &smem[2][ldA0]);
    GLDS(BT + br1*KP + (k0 + as1), &smem[2][ldA1]);
  }
  __syncthreads();

  int cur = 0;
  for (int it = 0; it < nit; ++it) {
    if (it + 1 < nit) {
      const int kn = k0beg + (it+1)*32;
      GLDS(A + ar0*lda + (kn + as0), &smem[cur^1][ldA0]);
      GLDS(A + ar1*lda + (kn + as1), &smem[cur^1][ldA1]);
      GLDS(BT + br0*KP + (kn + as0), &smem[2+(cur^1)][ldA0]);
      GLDS(BT + br1*KP + (kn + as1), &smem[2+(cur^1)][ldA1]);
    }

    short8 af[4], bf[4];
    #pragma unroll
    for (int m=0;m<4;m++) af[m] = *(const short8*)&smem[cur][(wm + m*16 + l15)*32 + kro];
    #pragma unroll
    for (int n=0;n<4;n++) bf[n] = *(const short8*)&smem[2+cur][(wn + n*16 + l15)*32 + kro];
    #pragma unroll
    for (int m=0;m<4;m++)
      #pragma unroll
      for (int n=0;n<4;n++)
        acc[m][n] = __builtin_amdgcn_mfma_f32_16x16x32_bf16(af[m], bf[n], acc[m][n], 0, 0, 0);

    __syncthreads();   // drains prefetch + all waves' ds_reads
    cur ^= 1;
  }

  // ---- full-line epilogue via per-wave LDS transpose ----
  // per wave: 16 rows x 64 cols fp32, row stride 68 (16B-aligned, conflict-light)
  float* eb = ((float*)smem) + wave*1088;   // 4*1088*4B = 17408B <= 32KB
  float* Cf = ((float*)Cvoid) + z*zstride;
  unsigned short* Cb = (unsigned short*)Cvoid;
  #pragma unroll
  for (int m=0;m<4;m++){
    #pragma unroll
    for (int n=0;n<4;n++)
      #pragma unroll
      for (int r2=0;r2<4;r2++)
        eb[(l4*4+r2)*68 + n*16 + l15] = acc[m][n][r2];
    __syncthreads();
    const int row0 = bm + wm + m*16;
    #pragma unroll
    for (int i=0;i<4;i++){
      int idx = i*64 + lane;          // 0..255 float4-chunks of the 16x64 tile
      int rr  = idx >> 4;             // 0..15
      int c4  = (idx & 15) * 4;       // 0,4,..,60
      int row = row0 + rr;
      int col = bn + wn + c4;
      if (row < M) {
        float4 v = *(float4*)&eb[rr*68 + c4];
        float vv[4] = {v.x, v.y, v.z, v.w};
        if (col + 3 < N) {
          #pragma unroll
          for (int j=0;j<4;j++){
            float zz = vv[j] + (bias ? bias[col+j] : 0.f);
            vv[j] = RELU ? fmaxf(zz, 0.f) : zz;
          }
          if (OUTB) {
            unsigned short o[4] = { f2b(vv[0]), f2b(vv[1]), f2b(vv[2]), f2b(vv[3]) };
            *(uint2*)&Cb[(long)row*ldc + col] = *(uint2*)o;
          } else {
            float4 ov = {vv[0], vv[1], vv[2], vv[3]};
            *(float4*)&Cf[(long)row*ldc + col] = ov;
          }
        } else {
          #pragma unroll
          for (int j=0;j<4;j++){
            int cc = col + j;
            if (cc < N) {
              float zz = vv[j] + (bias ? bias[cc] : 0.f);
              if (RELU) zz = fmaxf(zz, 0.f);
              if (OUTB) Cb[(long)row*ldc + cc] = f2b(zz);
              else      Cf[(long)row*ldc + cc] = zz;
            }
          }
        }
      }
    }
    __syncthreads();
  }
}

// ---------------- GCN aggregation (bf16 h, fp32 accumulate) ----------------
__global__ __launch_bounds__(256) void k_agg(const unsigned short* __restrict__ h,
    const int* __restrict__ rowptr, const int* __restrict__ colsrc,
    const float* __restrict__ dinv, const float* __restrict__ bias,
    float* __restrict__ out)
{
  int d = blockIdx.x;
  int t = threadIdx.x;                 // channel pair 2t,2t+1
  const unsigned* h32 = (const unsigned*)h;
  float di = dinv[d];
  int beg = rowptr[d], end = rowptr[d+1];
  float a0 = 0.f, a1 = 0.f;
  for (int e = beg; e < end; e++) {
    int s = colsrc[e];
    float cf = dinv[s]*di;
    unsigned v = h32[(long)s*256 + t];
    a0 += blo(v)*cf;
    a1 += bhi(v)*cf;
  }
  unsigned v = h32[(long)d*256 + t];
  float sc = di*di;
  a0 += blo(v)*sc;
  a1 += bhi(v)*sc;
  float2 o; o.x = a0 + bias[2*t]; o.y = a1 + bias[2*t+1];
  *(float2*)&out[(long)d*F_H + 2*t] = o;
}

// ---------------- GraphNorm: fused sum+sumsq, then normalize ----------------
#define STAT_ROWS 50
__global__ __launch_bounds__(512) void k_stats(const float* __restrict__ x,
    float* __restrict__ msum, float* __restrict__ ssum){
  int c = threadIdx.x;
  int r0 = blockIdx.x*STAT_ROWS;
  float s = 0.f, s2 = 0.f;
  for (int r=r0;r<r0+STAT_ROWS;r++){ float v = x[(long)r*F_H+c]; s += v; s2 += v*v; }
  atomicAdd(&msum[c], s);
  atomicAdd(&ssum[c], s2);
}
// mode 0: l0f=y, l0b=bf16(y), jkb=bf16(y); mode 1: loutb=bf16(y+l0f), jkb=max; mode 2: jkb=max
__global__ __launch_bounds__(512) void k_final(const float* __restrict__ x,
    const float* __restrict__ msum, const float* __restrict__ ssum,
    const float* __restrict__ w, const float* __restrict__ b, const float* __restrict__ a,
    float* __restrict__ l0f, unsigned short* __restrict__ loutb,
    unsigned short* __restrict__ jkb, int mode)
{
  int c = threadIdx.x;
  float mean = msum[c]*(1.f/N_NODES);
  float aa = a[c];
  float var = ssum[c]*(1.f/N_NODES) - mean*mean*aa*(2.f-aa);
  float inv = rsqrtf(var + EPSV);
  float am = aa*mean;
  float wc = w[c], bc = b[c];
  int r0 = blockIdx.x*STAT_ROWS;
  for (int r=r0;r<r0+STAT_ROWS;r++){
    long idx = (long)r*F_H+c;
    float y = fmaxf(wc*(x[idx]-am)*inv+bc, 0.f);
    if (mode == 0) {
      l0f[idx] = y;
      unsigned short q = f2b(y);
      loutb[idx] = q;
      jkb[idx] = q;
    } else if (mode == 1) {
      loutb[idx] = f2b(y + l0f[idx]);
      float cur = __uint_as_float(((unsigned)jkb[idx])<<16);
      jkb[idx] = f2b(fmaxf(cur, y));
    } else {
      float cur = __uint_as_float(((unsigned)jkb[idx])<<16);
      jkb[idx] = f2b(fmaxf(cur, y));
    }
  }
}

extern "C" void kernel_launch(void* const* d_in, const int* in_sizes, int n_in,
                              void* d_out, int out_size, void* d_ws, size_t ws_size,
                              hipStream_t stream) {
  (void)in_sizes; (void)n_in; (void)out_size; (void)ws_size;
  const float* x     = (const float*)d_in[0];
  const int*   ei    = (const int*)d_in[1];
  const int*   srcp  = ei;
  const int*   dstp  = ei + N_EDGES;
  const float* Wc[3]  = {(const float*)d_in[2], (const float*)d_in[4], (const float*)d_in[6]};
  const float* bc_[3] = {(const float*)d_in[3], (const float*)d_in[5], (const float*)d_in[7]};
  const float* lin1W = (const float*)d_in[8];
  const float* lin1b = (const float*)d_in[9];
  const float* lin2W = (const float*)d_in[10];
  const float* lin2b = (const float*)d_in[11];
  const float* gw[3] = {(const float*)d_in[12], (const float*)d_in[15], (const float*)d_in[18]};
  const float* gb[3] = {(const float*)d_in[13], (const float*)d_in[16], (const float*)d_in[19]};
  const float* ga[3] = {(const float*)d_in[14], (const float*)d_in[17], (const float*)d_in[20]};

  float* out = (float*)d_out;   // out_size = 92,880,000 floats

  // ---- d_out scratch layout (explicit, non-overlapping in time) ----
  float* l0 = out;
  unsigned short* xb   = (unsigned short*)(out + SZL);
  unsigned short* l0b  = (unsigned short*)(out + SZL);
  unsigned short* hinb = (unsigned short*)(out + SZL + ACT);
  unsigned short* jkb  = (unsigned short*)(out + SZL + 2*ACT);
  unsigned short* t_b  = (unsigned short*)(out + SZL + 3*ACT);
  float* p1            = out + 57200000L;

  // ---- ws layout (~74.6 MB) ----
  float* ws   = (float*)d_ws;
  float* p0   = ws;                         // conv0 partial z=0; reused as `agg` afterwards
  float* agg  = ws;
  unsigned short* f1b = (unsigned short*)(ws + SZL);            // lin1 out: ACT floats
  long off = SZL + ACT;
  unsigned short* W0T   = (unsigned short*)(ws + off); off += (long)F_H*KP0/2;
  unsigned short* W1T   = (unsigned short*)(ws + off); off += (long)F_H*F_H/2;
  unsigned short* W2T   = (unsigned short*)(ws + off); off += (long)F_H*F_H/2;
  unsigned short* l1WT  = (unsigned short*)(ws + off); off += (long)F_H*F_H/2;
  unsigned short* l2WT  = (unsigned short*)(ws + off); off += (long)NP2*F_H/2;
  float* dinv = ws + off;                   off += N_NODES;
  float* msum = ws + off;                   off += F_H;
  float* ssum = ws + off;                   off += F_H;
  int* deg    = (int*)(ws + off);           off += N_NODES;
  int* rowptr = (int*)(ws + off);           off += N_NODES + 1;
  int* cursor = (int*)(ws + off);           off += N_NODES;
  int* colsrc = (int*)(ws + off);

  // ---- CSR build ----
  k_zero_i<<<(N_NODES+255)/256,256,0,stream>>>(deg, N_NODES);
  k_degree<<<(N_EDGES+255)/256,256,0,stream>>>(dstp, deg);
  k_dinv<<<(N_NODES+255)/256,256,0,stream>>>(deg, dinv);
  k_scan<<<1,1024,0,stream>>>(deg, rowptr);
  k_copy_i<<<(N_NODES+255)/256,256,0,stream>>>(rowptr, cursor, N_NODES);
  k_scatter<<<(N_EDGES+255)/256,256,0,stream>>>(srcp, dstp, cursor, colsrc);

  // ---- conversions ----
  {
    long nx = (long)N_PAD*(KP0/8);
    k_cvt_x<<<(int)((nx+255)/256),256,0,stream>>>(x, xb);
    int n0 = F_H*KP0;   k_cvtT<<<(n0+255)/256,256,0,stream>>>(Wc[0], W0T, F_IN, F_H, F_H, KP0);
    int nh = F_H*F_H;   k_cvtT<<<(nh+255)/256,256,0,stream>>>(Wc[1], W1T, F_H, F_H, F_H, F_H);
                        k_cvtT<<<(nh+255)/256,256,0,stream>>>(Wc[2], W2T, F_H, F_H, F_H, F_H);
                        k_cvtT<<<(nh+255)/256,256,0,stream>>>(lin1W, l1WT, F_H, F_H, F_H, F_H);
    int n2 = NP2*F_H;   k_cvtT<<<(n2+255)/256,256,0,stream>>>(lin2W, l2WT, F_H, F_IN, NP2, F_H);
  }

  // ---- 3 GCN layers ----
  for (int i = 0; i < 3; i++) {
    if (i == 0) {
      // split-K=2: z=0 -> p0 (ws), z=1 -> p1 (d_out); zstride maps p0+zstride == p1
      long zs = p1 - p0;
      k_gb<0,0><<<dim3(F_H/128, N_PAD/128, 2),256,0,stream>>>(xb, W0T, nullptr, p0,
          N_NODES, F_H, KP0, KP0, F_H, KP0/2, zs);
      k_red<<<(int)((SZL/4+255)/256),256,0,stream>>>(p0, p1, t_b);   // xb dead by now
    } else {
      const unsigned short* Ain = (i==1) ? l0b : hinb;
      const unsigned short* Wt  = (i==1) ? W1T : W2T;
      k_gb<1,0><<<dim3(F_H/128, N_PAD/128, 1),256,0,stream>>>(Ain, Wt, nullptr, t_b,
          N_NODES, F_H, F_H, F_H, F_H, F_H, 0L);
    }
    k_agg<<<N_NODES,256,0,stream>>>(t_b, rowptr, colsrc, dinv, bc_[i], agg);
    k_zero_f<<<4,256,0,stream>>>(msum, 1024);   // msum+ssum contiguous
    k_stats<<<N_NODES/STAT_ROWS,512,0,stream>>>(agg, msum, ssum);
    k_final<<<N_NODES/STAT_ROWS,512,0,stream>>>(agg, msum, ssum, gw[i], gb[i], ga[i],
        l0, (i==0)? l0b : hinb, jkb, i);
  }

  // ---- head ----
  k_gb<1,1><<<dim3(F_H/128, N_PAD/128, 1),256,0,stream>>>(jkb, l1WT, lin1b, f1b,
      N_NODES, F_H, F_H, F_H, F_H, F_H, 0L);
  k_gb<0,0><<<dim3(NP2/128, N_PAD/128, 1),256,0,stream>>>(f1b, l2WT, lin2b, out,
      N_NODES, F_IN, F_H, F_H, F_IN, F_H, 0L);
}